// Round 7
// baseline (1375.925 us; speedup 1.0000x reference)
//
#include <hip/hip_runtime.h>
#include <math.h>

#define D 128
#define NB 8
#define LDH 136
#define LDF 132

using bf16x8 = __attribute__((ext_vector_type(8))) short;
using f32x4  = __attribute__((ext_vector_type(4))) float;

__device__ __forceinline__ float wave_allsum(float v) {
    #pragma unroll
    for (int off = 32; off; off >>= 1) v += __shfl_xor(v, off);
    return v;
}

__device__ __forceinline__ float wave_allmax(float v) {
    #pragma unroll
    for (int off = 32; off; off >>= 1) v = fmaxf(v, __shfl_xor(v, off));
    return v;
}

__device__ __forceinline__ unsigned short f2bf(float f) {
    union { float f; unsigned u; } v; v.f = f;
    unsigned r = v.u + 0x7FFFu + ((v.u >> 16) & 1u);
    return (unsigned short)(r >> 16);
}

__device__ __forceinline__ float bf2f(unsigned u16) {
    union { unsigned u; float f; } v; v.u = u16 << 16;
    return v.f;
}

__device__ __forceinline__ void split_store8(const float* v,
                                             unsigned short* dhi, unsigned short* dlo) {
    unsigned short h8[8], l8[8];
    #pragma unroll
    for (int j = 0; j < 8; ++j) {
        unsigned short hv = f2bf(v[j]);
        h8[j] = hv;
        l8[j] = f2bf(v[j] - bf2f(hv));
    }
    uint4 H, L;
    H.x = (unsigned)h8[0] | ((unsigned)h8[1] << 16);
    H.y = (unsigned)h8[2] | ((unsigned)h8[3] << 16);
    H.z = (unsigned)h8[4] | ((unsigned)h8[5] << 16);
    H.w = (unsigned)h8[6] | ((unsigned)h8[7] << 16);
    L.x = (unsigned)l8[0] | ((unsigned)l8[1] << 16);
    L.y = (unsigned)l8[2] | ((unsigned)l8[3] << 16);
    L.z = (unsigned)l8[4] | ((unsigned)l8[5] << 16);
    L.w = (unsigned)l8[6] | ((unsigned)l8[7] << 16);
    *(uint4*)dhi = H;
    *(uint4*)dlo = L;
}

__device__ __forceinline__ void amax_err(float* e, float d) {
    atomicMax((unsigned*)e, __float_as_uint(d));
}

#define MFMA3(acc, ah, al, bh, bl)                                         \
    acc = __builtin_amdgcn_mfma_f32_16x16x32_bf16(ah, bh, acc, 0, 0, 0);   \
    acc = __builtin_amdgcn_mfma_f32_16x16x32_bf16(ah, bl, acc, 0, 0, 0);   \
    acc = __builtin_amdgcn_mfma_f32_16x16x32_bf16(al, bh, acc, 0, 0, 0);

// ================= round-3 proven f32 path (produces the real output) ======

__global__ void __launch_bounds__(128) transform_kernel(
    const float* __restrict__ x, const float* __restrict__ W1,
    const float* __restrict__ b1, const float* __restrict__ g1, const float* __restrict__ bt1,
    const float* __restrict__ We1, const float* __restrict__ be1,
    float* __restrict__ h, float* __restrict__ A, float* __restrict__ B, int N)
{
    __shared__ float xs[NB][D];
    __shared__ float hs[NB][D];
    __shared__ float redS[2][NB], redQ[2][NB];
    const int t = threadIdx.x;
    const int wid = t >> 6, lane = t & 63;
    const int base = blockIdx.x * NB;

    for (int n = 0; n < NB; ++n) {
        int node = base + n;
        xs[n][t] = (node < N) ? x[(size_t)node * D + t] : 0.f;
    }
    __syncthreads();

    float acc[NB];
    float bb = b1[t];
    #pragma unroll
    for (int n = 0; n < NB; ++n) acc[n] = bb;
    for (int k = 0; k < D; ++k) {
        float w = W1[k * D + t];
        #pragma unroll
        for (int n = 0; n < NB; ++n) acc[n] += xs[n][k] * w;
    }
    #pragma unroll
    for (int n = 0; n < NB; ++n) {
        float s = wave_allsum(acc[n]);
        float q = wave_allsum(acc[n] * acc[n]);
        if (lane == 0) { redS[wid][n] = s; redQ[wid][n] = q; }
    }
    __syncthreads();
    float gg = g1[t], bt = bt1[t];
    #pragma unroll
    for (int n = 0; n < NB; ++n) {
        float s = redS[0][n] + redS[1][n];
        float q = redQ[0][n] + redQ[1][n];
        float m = s * (1.f / D);
        float v = q * (1.f / D) - m * m;
        float hv = (acc[n] - m) * rsqrtf(v + 1e-5f) * gg + bt;
        hv = fmaxf(hv, 0.f);
        hs[n][t] = hv;
        int node = base + n;
        if (node < N) h[(size_t)node * D + t] = hv;
    }
    __syncthreads();

    float accA[NB], accB[NB];
    float ba = be1[t];
    #pragma unroll
    for (int n = 0; n < NB; ++n) { accA[n] = ba; accB[n] = 0.f; }
    for (int k = 0; k < D; ++k) {
        float wa = We1[k * D + t];
        float wb = We1[(k + D) * D + t];
        #pragma unroll
        for (int n = 0; n < NB; ++n) { accA[n] += hs[n][k] * wa; accB[n] += hs[n][k] * wb; }
    }
    #pragma unroll
    for (int n = 0; n < NB; ++n) {
        int node = base + n;
        if (node < N) {
            A[(size_t)node * D + t] = accA[n];
            B[(size_t)node * D + t] = accB[n];
        }
    }
}

__global__ void __launch_bounds__(256) hist_kernel(const int* __restrict__ ei,
                                                   int* __restrict__ deg, int E) {
    int e = blockIdx.x * 256 + threadIdx.x;
    if (e < E) atomicAdd(&deg[ei[E + e]], 1);
}

__global__ void __launch_bounds__(1024) scan_kernel(const int* __restrict__ deg,
                                                    int* __restrict__ off,
                                                    int* __restrict__ cursor, int N) {
    __shared__ int partial[1024];
    const int t = threadIdx.x;
    const int chunk = (N + 1023) / 1024;
    const int start = t * chunk;
    const int end = min(start + chunk, N);
    int s = 0;
    for (int i = start; i < end; ++i) s += deg[i];
    partial[t] = s;
    __syncthreads();
    for (int d = 1; d < 1024; d <<= 1) {
        int v = (t >= d) ? partial[t - d] : 0;
        __syncthreads();
        if (t >= d) partial[t] += v;
        __syncthreads();
    }
    int run = (t == 0) ? 0 : partial[t - 1];
    for (int i = start; i < end; ++i) {
        off[i] = run;
        cursor[i] = run;
        run += deg[i];
    }
    if (t == 0) off[N] = partial[1023];
}

__global__ void __launch_bounds__(256) scatter_kernel(const int* __restrict__ ei,
                                                      int* __restrict__ cursor,
                                                      int* __restrict__ ssrc, int E) {
    int e = blockIdx.x * 256 + threadIdx.x;
    if (e < E) {
        int pos = atomicAdd(&cursor[ei[E + e]], 1);
        ssrc[pos] = ei[e];
    }
}

__global__ void __launch_bounds__(256) agg_kernel(
    const int* __restrict__ off, const int* __restrict__ ssrc,
    const float* __restrict__ A, const float* __restrict__ B,
    const float* __restrict__ We2, const float* __restrict__ be2,
    const float* __restrict__ h, float* __restrict__ aggr, int N)
{
    const int wid = threadIdx.x >> 6, lane = threadIdx.x & 63;
    const int node = blockIdx.x * 4 + wid;
    if (node >= N) return;
    const float2 b = ((const float2*)(B + (size_t)node * D))[lane];
    const float2 ww = ((const float2*)We2)[lane];
    const float be = be2[0];
    float2 acc = make_float2(0.f, 0.f);
    const int s = off[node], e = off[node + 1];
    for (int j = s; j < e; ++j) {
        int src = ssrc[j];
        float2 a = ((const float2*)(A + (size_t)src * D))[lane];
        float2 hv = ((const float2*)(h + (size_t)src * D))[lane];
        float part = fmaxf(a.x + b.x, 0.f) * ww.x + fmaxf(a.y + b.y, 0.f) * ww.y;
        part = wave_allsum(part);
        float w = 1.f / (1.f + expf(-(part + be)));
        acc.x += w * hv.x;
        acc.y += w * hv.y;
    }
    ((float2*)(aggr + (size_t)node * D))[lane] = acc;
}

__global__ void __launch_bounds__(128) gate_kernel(
    const float* __restrict__ h, const float* __restrict__ aggr,
    const float* __restrict__ Wg, const float* __restrict__ bg,
    const float* __restrict__ g2, const float* __restrict__ bt2,
    float* __restrict__ out, int N)
{
    __shared__ float hs[NB][D], as_[NB][D];
    __shared__ float redS[2][NB], redQ[2][NB];
    const int t = threadIdx.x, wid = t >> 6, lane = t & 63;
    const int base = blockIdx.x * NB;
    for (int n = 0; n < NB; ++n) {
        int node = base + n;
        hs[n][t]  = (node < N) ? h[(size_t)node * D + t] : 0.f;
        as_[n][t] = (node < N) ? aggr[(size_t)node * D + t] : 0.f;
    }
    __syncthreads();
    float acc[NB];
    float bb = bg[t];
    #pragma unroll
    for (int n = 0; n < NB; ++n) acc[n] = bb;
    for (int k = 0; k < D; ++k) {
        float wt = Wg[k * D + t], wb = Wg[(k + D) * D + t];
        #pragma unroll
        for (int n = 0; n < NB; ++n) acc[n] += hs[n][k] * wt + as_[n][k] * wb;
    }
    float gg = g2[t], bt = bt2[t];
    float hn[NB];
    #pragma unroll
    for (int n = 0; n < NB; ++n) {
        float gate = 1.f / (1.f + expf(-acc[n]));
        hn[n] = gate * as_[n][t] + (1.f - gate) * hs[n][t];
        float s = wave_allsum(hn[n]);
        float q = wave_allsum(hn[n] * hn[n]);
        if (lane == 0) { redS[wid][n] = s; redQ[wid][n] = q; }
    }
    __syncthreads();
    #pragma unroll
    for (int n = 0; n < NB; ++n) {
        int node = base + n;
        if (node >= N) continue;
        float s = redS[0][n] + redS[1][n];
        float q = redQ[0][n] + redQ[1][n];
        float m = s * (1.f / D);
        float v = q * (1.f / D) - m * m;
        out[(size_t)node * D + t] = (hn[n] - m) * rsqrtf(v + 1e-5f) * gg + bt;
    }
}

// ================= diagnostic shadow path (compares, never writes tensors) ==

__global__ void __launch_bounds__(256) prep_weights(
    const float* __restrict__ W1, const float* __restrict__ We1, const float* __restrict__ Wg,
    unsigned short* __restrict__ W1Th, unsigned short* __restrict__ W1Tl,
    unsigned short* __restrict__ We1Th, unsigned short* __restrict__ We1Tl,
    unsigned short* __restrict__ WgTh, unsigned short* __restrict__ WgTl)
{
    int i = blockIdx.x * 256 + threadIdx.x;
    float w; unsigned short *dh, *dl; int idx;
    if (i < 16384) {
        int n = i >> 7, k = i & 127;
        w = W1[k * 128 + n]; dh = W1Th; dl = W1Tl; idx = i;
    } else if (i < 49152) {
        int j = i - 16384; int n = j >> 8, k = j & 255;
        w = We1[k * 128 + n]; dh = We1Th; dl = We1Tl; idx = j;
    } else if (i < 81920) {
        int j = i - 49152; int n = j >> 8, k = j & 255;
        w = Wg[k * 128 + n]; dh = WgTh; dl = WgTl; idx = j;
    } else return;
    unsigned short hv = f2bf(w);
    dh[idx] = hv;
    dl[idx] = f2bf(w - bf2f(hv));
}

// err[0]=raw GEMM1 mfma vs direct dot; err[1]=h; err[2]=A; err[3]=B
__global__ void __launch_bounds__(256) transform_mfma_check(
    const float* __restrict__ x,
    const unsigned short* __restrict__ W1Th, const unsigned short* __restrict__ W1Tl,
    const float* __restrict__ b1,
    const float* __restrict__ g1, const float* __restrict__ bt1,
    const unsigned short* __restrict__ We1Th, const unsigned short* __restrict__ We1Tl,
    const float* __restrict__ be1,
    const float* __restrict__ h, const float* __restrict__ A, const float* __restrict__ B,
    float* __restrict__ err, int N)
{
    __shared__ unsigned short xhi[16][LDH], xlo[16][LDH];
    __shared__ unsigned short hhi[16][LDH], hlo[16][LDH];
    __shared__ float yf[16][LDF];
    const int t = threadIdx.x;
    const int wid = t >> 6, lane = t & 63;
    const int base = blockIdx.x * 16;
    const int am = lane & 15;
    const int kb = (lane >> 4) * 8;
    const int n0 = wid * 32;

    {
        int node = t >> 4, c0 = (t & 15) * 8;
        int gn = min(base + node, N - 1);
        const float* src = x + (size_t)gn * D + c0;
        float v[8];
        float4 v0 = *(const float4*)src, v1 = *(const float4*)(src + 4);
        v[0]=v0.x; v[1]=v0.y; v[2]=v0.z; v[3]=v0.w;
        v[4]=v1.x; v[5]=v1.y; v[6]=v1.z; v[7]=v1.w;
        split_store8(v, &xhi[node][c0], &xlo[node][c0]);
    }
    __syncthreads();

    f32x4 acc0 = {0.f,0.f,0.f,0.f}, acc1 = {0.f,0.f,0.f,0.f};
    #pragma unroll
    for (int ks = 0; ks < 4; ++ks) {
        bf16x8 ah = *(const bf16x8*)&xhi[am][ks * 32 + kb];
        bf16x8 al = *(const bf16x8*)&xlo[am][ks * 32 + kb];
        size_t o0 = (size_t)(n0 + am) * 128 + ks * 32 + kb;
        size_t o1 = (size_t)(n0 + 16 + am) * 128 + ks * 32 + kb;
        bf16x8 bh0 = *(const bf16x8*)&W1Th[o0], bl0 = *(const bf16x8*)&W1Tl[o0];
        bf16x8 bh1 = *(const bf16x8*)&W1Th[o1], bl1 = *(const bf16x8*)&W1Tl[o1];
        MFMA3(acc0, ah, al, bh0, bl0);
        MFMA3(acc1, ah, al, bh1, bl1);
    }

    // direct-dot check of acc0[0]: D[row0][n0+am] must equal sum_k X[row0][k]*W1[k][n0+am]
    {
        int col = n0 + am;
        int row0 = (lane >> 4) * 4;
        float ref = 0.f;
        for (int k = 0; k < 128; ++k) {
            float xv = bf2f(xhi[row0][k]) + bf2f(xlo[row0][k]);
            float wv = bf2f(W1Th[(size_t)col * 128 + k]) + bf2f(W1Tl[(size_t)col * 128 + k]);
            ref += xv * wv;
        }
        float d = wave_allmax(fabsf(acc0[0] - ref));
        if (lane == 0) amax_err(&err[0], d);
    }

    {
        float bia0 = b1[n0 + am], bia1 = b1[n0 + 16 + am];
        #pragma unroll
        for (int r = 0; r < 4; ++r) {
            int row = (lane >> 4) * 4 + r;
            yf[row][n0 + am]      = acc0[r] + bia0;
            yf[row][n0 + 16 + am] = acc1[r] + bia1;
        }
    }
    __syncthreads();

    {
        float gg0 = g1[2*lane], gg1 = g1[2*lane+1];
        float bb0 = bt1[2*lane], bb1 = bt1[2*lane+1];
        float dmax = 0.f;
        #pragma unroll
        for (int i = 0; i < 4; ++i) {
            int node = wid * 4 + i;
            float v0 = yf[node][2*lane], v1 = yf[node][2*lane+1];
            float s = wave_allsum(v0 + v1);
            float q = wave_allsum(v0*v0 + v1*v1);
            float m = s * (1.f/128.f);
            float var = q * (1.f/128.f) - m*m;
            float rs = rsqrtf(var + 1e-5f);
            float h0 = fmaxf((v0 - m)*rs*gg0 + bb0, 0.f);
            float h1 = fmaxf((v1 - m)*rs*gg1 + bb1, 0.f);
            unsigned short p0 = f2bf(h0), p1 = f2bf(h1);
            *(unsigned*)&hhi[node][2*lane] = (unsigned)p0 | ((unsigned)p1 << 16);
            *(unsigned*)&hlo[node][2*lane] =
                (unsigned)f2bf(h0 - bf2f(p0)) | ((unsigned)f2bf(h1 - bf2f(p1)) << 16);
            float2 hr = *(const float2*)&h[(size_t)(base + node) * D + 2*lane];
            dmax = fmaxf(dmax, fmaxf(fabsf(h0 - hr.x), fabsf(h1 - hr.y)));
        }
        float d = wave_allmax(dmax);
        if (lane == 0) amax_err(&err[1], d);
    }
    __syncthreads();

    f32x4 aA0 = {0.f,0.f,0.f,0.f}, aA1 = {0.f,0.f,0.f,0.f};
    f32x4 aB0 = {0.f,0.f,0.f,0.f}, aB1 = {0.f,0.f,0.f,0.f};
    #pragma unroll
    for (int ks = 0; ks < 4; ++ks) {
        bf16x8 ah = *(const bf16x8*)&hhi[am][ks * 32 + kb];
        bf16x8 al = *(const bf16x8*)&hlo[am][ks * 32 + kb];
        size_t t0 = (size_t)(n0 + am) * 256 + ks * 32 + kb;
        size_t t1 = (size_t)(n0 + 16 + am) * 256 + ks * 32 + kb;
        bf16x8 bth0 = *(const bf16x8*)&We1Th[t0], btl0 = *(const bf16x8*)&We1Tl[t0];
        bf16x8 bth1 = *(const bf16x8*)&We1Th[t1], btl1 = *(const bf16x8*)&We1Tl[t1];
        bf16x8 bbh0 = *(const bf16x8*)&We1Th[t0 + 128], bbl0 = *(const bf16x8*)&We1Tl[t0 + 128];
        bf16x8 bbh1 = *(const bf16x8*)&We1Th[t1 + 128], bbl1 = *(const bf16x8*)&We1Tl[t1 + 128];
        MFMA3(aA0, ah, al, bth0, btl0);
        MFMA3(aA1, ah, al, bth1, btl1);
        MFMA3(aB0, ah, al, bbh0, bbl0);
        MFMA3(aB1, ah, al, bbh1, bbl1);
    }
    {
        float beA0 = be1[n0 + am], beA1 = be1[n0 + 16 + am];
        float dA = 0.f, dB = 0.f;
        #pragma unroll
        for (int r = 0; r < 4; ++r) {
            int row = (lane >> 4) * 4 + r;
            int gn = base + row;
            size_t g0 = (size_t)gn * D + n0 + am;
            size_t g1i = (size_t)gn * D + n0 + 16 + am;
            dA = fmaxf(dA, fabsf(aA0[r] + beA0 - A[g0]));
            dA = fmaxf(dA, fabsf(aA1[r] + beA1 - A[g1i]));
            dB = fmaxf(dB, fabsf(aB0[r] - B[g0]));
            dB = fmaxf(dB, fabsf(aB1[r] - B[g1i]));
        }
        dA = wave_allmax(dA); dB = wave_allmax(dB);
        if (lane == 0) { amax_err(&err[2], dA); amax_err(&err[3], dB); }
    }
}

// err[4]: full MFMA gate path vs d_out
__global__ void __launch_bounds__(256) gate_mfma_check(
    const float* __restrict__ h, const float* __restrict__ aggr,
    const unsigned short* __restrict__ WgTh, const unsigned short* __restrict__ WgTl,
    const float* __restrict__ bg,
    const float* __restrict__ g2, const float* __restrict__ bt2,
    const float* __restrict__ out, float* __restrict__ err, int N)
{
    __shared__ unsigned short hhi[16][LDH], hlo[16][LDH];
    __shared__ unsigned short ahi[16][LDH], alo[16][LDH];
    __shared__ float yf[16][LDF];
    const int t = threadIdx.x;
    const int wid = t >> 6, lane = t & 63;
    const int base = blockIdx.x * 16;
    const int am = lane & 15;
    const int kb = (lane >> 4) * 8;
    const int n0 = wid * 32;

    {
        int node = t >> 4, c0 = (t & 15) * 8;
        size_t g = (size_t)min(base + node, N - 1) * D + c0;
        float v[8];
        float4 u0 = *(const float4*)&h[g], u1 = *(const float4*)&h[g + 4];
        v[0]=u0.x; v[1]=u0.y; v[2]=u0.z; v[3]=u0.w;
        v[4]=u1.x; v[5]=u1.y; v[6]=u1.z; v[7]=u1.w;
        split_store8(v, &hhi[node][c0], &hlo[node][c0]);
        float4 a0 = *(const float4*)&aggr[g], a1 = *(const float4*)&aggr[g + 4];
        v[0]=a0.x; v[1]=a0.y; v[2]=a0.z; v[3]=a0.w;
        v[4]=a1.x; v[5]=a1.y; v[6]=a1.z; v[7]=a1.w;
        split_store8(v, &ahi[node][c0], &alo[node][c0]);
    }
    __syncthreads();

    f32x4 acc0 = {0.f,0.f,0.f,0.f}, acc1 = {0.f,0.f,0.f,0.f};
    #pragma unroll
    for (int ks = 0; ks < 4; ++ks) {
        size_t o0 = (size_t)(n0 + am) * 256 + ks * 32 + kb;
        size_t o1 = (size_t)(n0 + 16 + am) * 256 + ks * 32 + kb;
        {
            bf16x8 ah = *(const bf16x8*)&hhi[am][ks * 32 + kb];
            bf16x8 al = *(const bf16x8*)&hlo[am][ks * 32 + kb];
            bf16x8 bh0 = *(const bf16x8*)&WgTh[o0], bl0 = *(const bf16x8*)&WgTl[o0];
            bf16x8 bh1 = *(const bf16x8*)&WgTh[o1], bl1 = *(const bf16x8*)&WgTl[o1];
            MFMA3(acc0, ah, al, bh0, bl0);
            MFMA3(acc1, ah, al, bh1, bl1);
        }
        {
            bf16x8 ah = *(const bf16x8*)&ahi[am][ks * 32 + kb];
            bf16x8 al = *(const bf16x8*)&alo[am][ks * 32 + kb];
            bf16x8 bh0 = *(const bf16x8*)&WgTh[o0 + 128], bl0 = *(const bf16x8*)&WgTl[o0 + 128];
            bf16x8 bh1 = *(const bf16x8*)&WgTh[o1 + 128], bl1 = *(const bf16x8*)&WgTl[o1 + 128];
            MFMA3(acc0, ah, al, bh0, bl0);
            MFMA3(acc1, ah, al, bh1, bl1);
        }
    }
    {
        float bg0 = bg[n0 + am], bg1 = bg[n0 + 16 + am];
        #pragma unroll
        for (int r = 0; r < 4; ++r) {
            int row = (lane >> 4) * 4 + r;
            int c0 = n0 + am, c1 = n0 + 16 + am;
            float g0 = 1.f / (1.f + expf(-(acc0[r] + bg0)));
            float g1v= 1.f / (1.f + expf(-(acc1[r] + bg1)));
            float hv0 = bf2f(hhi[row][c0]) + bf2f(hlo[row][c0]);
            float av0 = bf2f(ahi[row][c0]) + bf2f(alo[row][c0]);
            float hv1 = bf2f(hhi[row][c1]) + bf2f(hlo[row][c1]);
            float av1 = bf2f(ahi[row][c1]) + bf2f(alo[row][c1]);
            yf[row][c0] = g0 * av0 + (1.f - g0) * hv0;
            yf[row][c1] = g1v * av1 + (1.f - g1v) * hv1;
        }
    }
    __syncthreads();

    {
        float gg0 = g2[2*lane], gg1 = g2[2*lane+1];
        float bb0 = bt2[2*lane], bb1 = bt2[2*lane+1];
        float dmax = 0.f;
        #pragma unroll
        for (int i = 0; i < 4; ++i) {
            int node = wid * 4 + i;
            float v0 = yf[node][2*lane], v1 = yf[node][2*lane+1];
            float s = wave_allsum(v0 + v1);
            float q = wave_allsum(v0*v0 + v1*v1);
            float m = s * (1.f/128.f);
            float var = q * (1.f/128.f) - m*m;
            float rs = rsqrtf(var + 1e-5f);
            float o0 = (v0 - m)*rs*gg0 + bb0;
            float o1 = (v1 - m)*rs*gg1 + bb1;
            float2 orf = *(const float2*)&out[(size_t)(base + node) * D + 2*lane];
            dmax = fmaxf(dmax, fmaxf(fabsf(o0 - orf.x), fabsf(o1 - orf.y)));
        }
        float d = wave_allmax(dmax);
        if (lane == 0) amax_err(&err[4], d);
    }
}

__device__ __forceinline__ void spin_if(float e, float thr, long long cyc) {
    if (e > thr) {
        long long t0 = clock64();
        while (clock64() - t0 < cyc) __builtin_amdgcn_s_sleep(8);
    }
}
__global__ void diag_y_bad(const float* err)   { spin_if(err[0], 0.02f,  300000); }
__global__ void diag_h_bad(const float* err)   { spin_if(err[1], 0.02f,  600000); }
__global__ void diag_A_bad(const float* err)   { spin_if(err[2], 0.02f,  900000); }
__global__ void diag_B_bad(const float* err)   { spin_if(err[3], 0.02f, 1200000); }
__global__ void diag_out_bad(const float* err) { spin_if(err[4], 0.05f, 1500000); }

extern "C" void kernel_launch(void* const* d_in, const int* in_sizes, int n_in,
                              void* d_out, int out_size, void* d_ws, size_t ws_size,
                              hipStream_t stream) {
    const float* x   = (const float*)d_in[0];
    const int*   ei  = (const int*)d_in[1];
    const float* W1  = (const float*)d_in[2];
    const float* b1  = (const float*)d_in[3];
    const float* g1  = (const float*)d_in[4];
    const float* bt1 = (const float*)d_in[5];
    const float* We1 = (const float*)d_in[6];
    const float* be1 = (const float*)d_in[7];
    const float* We2 = (const float*)d_in[8];
    const float* be2 = (const float*)d_in[9];
    const float* Wg  = (const float*)d_in[14];
    const float* bg  = (const float*)d_in[15];
    const float* g2  = (const float*)d_in[16];
    const float* bt2 = (const float*)d_in[17];

    const int N = in_sizes[0] / D;
    const int E = in_sizes[1] / 2;
    const size_t ND = (size_t)N * D;

    float* h    = (float*)d_ws;
    float* A    = h + ND;
    float* B    = A + ND;
    float* aggr = B + ND;
    unsigned short* W1Th  = (unsigned short*)(aggr + ND);
    unsigned short* W1Tl  = W1Th + 16384;
    unsigned short* We1Th = W1Tl + 16384;
    unsigned short* We1Tl = We1Th + 32768;
    unsigned short* WgTh  = We1Tl + 32768;
    unsigned short* WgTl  = WgTh + 32768;
    int* deg    = (int*)(WgTl + 32768);
    int* off    = deg + (N + 1);
    int* cursor = off + (N + 1);
    int* ssrc   = cursor + (N + 1);
    float* err  = (float*)(ssrc + E);

    (void)hipMemsetAsync(deg, 0, (size_t)(N + 1) * sizeof(int), stream);
    (void)hipMemsetAsync(err, 0, 8 * sizeof(float), stream);

    prep_weights<<<320, 256, 0, stream>>>(W1, We1, Wg, W1Th, W1Tl, We1Th, We1Tl, WgTh, WgTl);
    hist_kernel<<<(E + 255) / 256, 256, 0, stream>>>(ei, deg, E);
    scan_kernel<<<1, 1024, 0, stream>>>(deg, off, cursor, N);
    scatter_kernel<<<(E + 255) / 256, 256, 0, stream>>>(ei, cursor, ssrc, E);

    const int nblk = (N + NB - 1) / NB;
    transform_kernel<<<nblk, 128, 0, stream>>>(x, W1, b1, g1, bt1, We1, be1, h, A, B, N);
    agg_kernel<<<(N + 3) / 4, 256, 0, stream>>>(off, ssrc, A, B, We2, be2, h, aggr, N);
    gate_kernel<<<nblk, 128, 0, stream>>>(h, aggr, Wg, bg, g2, bt2, (float*)d_out, N);

    // shadow diagnostics (read-only on all tensors)
    const int nblk16 = (N + 15) / 16;
    transform_mfma_check<<<nblk16, 256, 0, stream>>>(x, W1Th, W1Tl, b1, g1, bt1,
                                                     We1Th, We1Tl, be1, h, A, B, err, N);
    gate_mfma_check<<<nblk16, 256, 0, stream>>>(h, aggr, WgTh, WgTl, bg, g2, bt2,
                                                (const float*)d_out, err, N);
    diag_y_bad<<<1, 64, 0, stream>>>(err);
    diag_h_bad<<<1, 64, 0, stream>>>(err);
    diag_A_bad<<<1, 64, 0, stream>>>(err);
    diag_B_bad<<<1, 64, 0, stream>>>(err);
    diag_out_bad<<<1, 64, 0, stream>>>(err);
}

// Round 8
// 688.090 us; speedup vs baseline: 1.9996x; 1.9996x over previous
//
#include <hip/hip_runtime.h>
#include <math.h>

#define D 128
#define NT 16
#define LDS_PAD 132
#define LDH 136

using bf16x8 = __attribute__((ext_vector_type(8))) short;
using f32x4  = __attribute__((ext_vector_type(4))) float;

__device__ __forceinline__ float wave_allsum(float v) {
    #pragma unroll
    for (int off = 32; off; off >>= 1) v += __shfl_xor(v, off);
    return v;
}

__device__ __forceinline__ float wave_allmax(float v) {
    #pragma unroll
    for (int off = 32; off; off >>= 1) v = fmaxf(v, __shfl_xor(v, off));
    return v;
}

__device__ __forceinline__ unsigned short f2bf(float f) {
    union { float f; unsigned u; } v; v.f = f;
    unsigned r = v.u + 0x7FFFu + ((v.u >> 16) & 1u);
    return (unsigned short)(r >> 16);
}

__device__ __forceinline__ float bf2f(unsigned u16) {
    union { unsigned u; float f; } v; v.u = u16 << 16;
    return v.f;
}

__device__ __forceinline__ void split_store8(const float* v,
                                             unsigned short* dhi, unsigned short* dlo) {
    unsigned short h8[8], l8[8];
    #pragma unroll
    for (int j = 0; j < 8; ++j) {
        unsigned short hv = f2bf(v[j]);
        h8[j] = hv;
        l8[j] = f2bf(v[j] - bf2f(hv));
    }
    uint4 H, L;
    H.x = (unsigned)h8[0] | ((unsigned)h8[1] << 16);
    H.y = (unsigned)h8[2] | ((unsigned)h8[3] << 16);
    H.z = (unsigned)h8[4] | ((unsigned)h8[5] << 16);
    H.w = (unsigned)h8[6] | ((unsigned)h8[7] << 16);
    L.x = (unsigned)l8[0] | ((unsigned)l8[1] << 16);
    L.y = (unsigned)l8[2] | ((unsigned)l8[3] << 16);
    L.z = (unsigned)l8[4] | ((unsigned)l8[5] << 16);
    L.w = (unsigned)l8[6] | ((unsigned)l8[7] << 16);
    *(uint4*)dhi = H;
    *(uint4*)dlo = L;
}

__device__ __forceinline__ void amax_err(float* e, float d) {
    atomicMax((unsigned*)e, __float_as_uint(d));
}

#define MFMA3(acc, ah, al, bh, bl)                                         \
    acc = __builtin_amdgcn_mfma_f32_16x16x32_bf16(ah, bh, acc, 0, 0, 0);   \
    acc = __builtin_amdgcn_mfma_f32_16x16x32_bf16(ah, bl, acc, 0, 0, 0);   \
    acc = __builtin_amdgcn_mfma_f32_16x16x32_bf16(al, bh, acc, 0, 0, 0);

// ======================= weight prep =======================

// f32 transposes: W1Tf[n][k]=W1[k][n]; We1Tf[n][0..255]; WgTf[n][0..255]
__global__ void __launch_bounds__(256) prep_wf32(
    const float* __restrict__ W1, const float* __restrict__ We1, const float* __restrict__ Wg,
    float* __restrict__ W1Tf, float* __restrict__ We1Tf, float* __restrict__ WgTf)
{
    int i = blockIdx.x * 256 + threadIdx.x;
    if (i < 16384) {
        int n = i >> 7, k = i & 127;
        W1Tf[i] = W1[k * 128 + n];
    } else if (i < 49152) {
        int j = i - 16384; int n = j >> 8, k = j & 255;
        We1Tf[j] = We1[k * 128 + n];
    } else if (i < 81920) {
        int j = i - 49152; int n = j >> 8, k = j & 255;
        WgTf[j] = Wg[k * 128 + n];
    }
}

// bf16 hi/lo transposes (diagnostic shadow path)
__global__ void __launch_bounds__(256) prep_wbf(
    const float* __restrict__ W1, const float* __restrict__ We1, const float* __restrict__ Wg,
    unsigned short* __restrict__ W1Th, unsigned short* __restrict__ W1Tl,
    unsigned short* __restrict__ We1Th, unsigned short* __restrict__ We1Tl,
    unsigned short* __restrict__ WgTh, unsigned short* __restrict__ WgTl)
{
    int i = blockIdx.x * 256 + threadIdx.x;
    float w; unsigned short *dh, *dl; int idx;
    if (i < 16384) {
        int n = i >> 7, k = i & 127;
        w = W1[k * 128 + n]; dh = W1Th; dl = W1Tl; idx = i;
    } else if (i < 49152) {
        int j = i - 16384; int n = j >> 8, k = j & 255;
        w = We1[k * 128 + n]; dh = We1Th; dl = We1Tl; idx = j;
    } else if (i < 81920) {
        int j = i - 49152; int n = j >> 8, k = j & 255;
        w = Wg[k * 128 + n]; dh = WgTh; dl = WgTl; idx = j;
    } else return;
    unsigned short hv = f2bf(w);
    dh[idx] = hv;
    dl[idx] = f2bf(w - bf2f(hv));
}

// ======================= production path (f32) =======================

// 16 nodes/block, 256 threads. col = t&127, half = t>>7 owns 8 nodes.
__global__ void __launch_bounds__(256) transform_v2(
    const float* __restrict__ x, const float* __restrict__ W1Tf, const float* __restrict__ b1,
    const float* __restrict__ g1, const float* __restrict__ bt1,
    const float* __restrict__ We1Tf, const float* __restrict__ be1,
    float* __restrict__ h, float* __restrict__ A, float* __restrict__ B, int N)
{
    __shared__ float xs[NT][LDS_PAD];
    __shared__ float ys[NT][LDS_PAD];
    const int t = threadIdx.x;
    const int col = t & 127;
    const int half = t >> 7;
    const int wid = t >> 6, lane = t & 63;
    const int base = blockIdx.x * NT;

    {
        int node = t >> 4, c0 = (t & 15) * 8;
        int gn = min(base + node, N - 1);
        const float4* src = (const float4*)(x + (size_t)gn * D + c0);
        *(float4*)&xs[node][c0]     = src[0];
        *(float4*)&xs[node][c0 + 4] = src[1];
    }
    __syncthreads();

    // GEMM1: y = x @ W1
    float acc[8];
    #pragma unroll
    for (int n = 0; n < 8; ++n) acc[n] = 0.f;
    {
        const float* wcol = W1Tf + (size_t)col * 128;
        for (int k4 = 0; k4 < 32; ++k4) {
            float4 w = *(const float4*)(wcol + k4 * 4);
            #pragma unroll
            for (int n = 0; n < 8; ++n) {
                float4 xv = *(const float4*)&xs[half * 8 + n][k4 * 4];
                acc[n] += xv.x * w.x + xv.y * w.y + xv.z * w.z + xv.w * w.w;
            }
        }
    }
    {
        float bia = b1[col];
        #pragma unroll
        for (int n = 0; n < 8; ++n) ys[half * 8 + n][col] = acc[n] + bia;
    }
    __syncthreads();

    // LN + relu; h -> global f32 + xs reused as h-tile
    {
        float gg0 = g1[2*lane], gg1 = g1[2*lane+1];
        float bb0 = bt1[2*lane], bb1 = bt1[2*lane+1];
        #pragma unroll
        for (int i = 0; i < 4; ++i) {
            int node = wid * 4 + i;
            float v0 = ys[node][2*lane], v1 = ys[node][2*lane+1];
            float s = wave_allsum(v0 + v1);
            float q = wave_allsum(v0*v0 + v1*v1);
            float m = s * (1.f/128.f);
            float var = q * (1.f/128.f) - m*m;
            float rs = rsqrtf(var + 1e-5f);
            float h0 = fmaxf((v0 - m)*rs*gg0 + bb0, 0.f);
            float h1 = fmaxf((v1 - m)*rs*gg1 + bb1, 0.f);
            *(float2*)&xs[node][2*lane] = make_float2(h0, h1);
            if (base + node < N)
                *(float2*)&h[(size_t)(base + node) * D + 2*lane] = make_float2(h0, h1);
        }
    }
    __syncthreads();

    // GEMM2: A = h@We1_top + be1 ; B = h@We1_bot
    float accA[8], accB[8];
    #pragma unroll
    for (int n = 0; n < 8; ++n) { accA[n] = 0.f; accB[n] = 0.f; }
    {
        const float* wacol = We1Tf + (size_t)col * 256;
        for (int k4 = 0; k4 < 32; ++k4) {
            float4 wa = *(const float4*)(wacol + k4 * 4);
            float4 wb = *(const float4*)(wacol + 128 + k4 * 4);
            #pragma unroll
            for (int n = 0; n < 8; ++n) {
                float4 hv = *(const float4*)&xs[half * 8 + n][k4 * 4];
                accA[n] += hv.x * wa.x + hv.y * wa.y + hv.z * wa.z + hv.w * wa.w;
                accB[n] += hv.x * wb.x + hv.y * wb.y + hv.z * wb.z + hv.w * wb.w;
            }
        }
    }
    {
        float beA = be1[col];
        #pragma unroll
        for (int n = 0; n < 8; ++n) {
            int gn = base + half * 8 + n;
            if (gn < N) {
                A[(size_t)gn * D + col] = accA[n] + beA;
                B[(size_t)gn * D + col] = accB[n];
            }
        }
    }
}

// ---- CSR build ----
__global__ void __launch_bounds__(256) hist_kernel(const int* __restrict__ ei,
                                                   int* __restrict__ deg, int E) {
    int e = blockIdx.x * 256 + threadIdx.x;
    if (e < E) atomicAdd(&deg[ei[E + e]], 1);
}

__global__ void __launch_bounds__(1024) scan_kernel(const int* __restrict__ deg,
                                                    int* __restrict__ off,
                                                    int* __restrict__ cursor, int N) {
    __shared__ int partial[1024];
    const int t = threadIdx.x;
    const int chunk = (N + 1023) / 1024;
    const int start = t * chunk;
    const int end = min(start + chunk, N);
    int s = 0;
    for (int i = start; i < end; ++i) s += deg[i];
    partial[t] = s;
    __syncthreads();
    for (int d = 1; d < 1024; d <<= 1) {
        int v = (t >= d) ? partial[t - d] : 0;
        __syncthreads();
        if (t >= d) partial[t] += v;
        __syncthreads();
    }
    int run = (t == 0) ? 0 : partial[t - 1];
    for (int i = start; i < end; ++i) {
        off[i] = run;
        cursor[i] = run;
        run += deg[i];
    }
    if (t == 0) off[N] = partial[1023];
}

__global__ void __launch_bounds__(256) scatter_kernel(const int* __restrict__ ei,
                                                      int* __restrict__ cursor,
                                                      int* __restrict__ ssrc, int E) {
    int e = blockIdx.x * 256 + threadIdx.x;
    if (e < E) {
        int pos = atomicAdd(&cursor[ei[E + e]], 1);
        ssrc[pos] = ei[e];
    }
}

// pull aggregation, 2-edge interleaved unroll
__global__ void __launch_bounds__(256) agg_v2(
    const int* __restrict__ off, const int* __restrict__ ssrc,
    const float* __restrict__ A, const float* __restrict__ B,
    const float* __restrict__ We2, const float* __restrict__ be2,
    const float* __restrict__ h, float* __restrict__ aggr, int N)
{
    const int wid = threadIdx.x >> 6, lane = threadIdx.x & 63;
    const int node = blockIdx.x * 4 + wid;
    if (node >= N) return;
    const float2 b = ((const float2*)(B + (size_t)node * D))[lane];
    const float2 ww = ((const float2*)We2)[lane];
    const float be = be2[0];
    float2 acc = make_float2(0.f, 0.f);
    const int s = off[node], e = off[node + 1];
    int j = s;
    for (; j + 1 < e; j += 2) {
        int s0 = ssrc[j], s1 = ssrc[j + 1];
        float2 a0 = ((const float2*)(A + (size_t)s0 * D))[lane];
        float2 h0 = ((const float2*)(h + (size_t)s0 * D))[lane];
        float2 a1 = ((const float2*)(A + (size_t)s1 * D))[lane];
        float2 h1 = ((const float2*)(h + (size_t)s1 * D))[lane];
        float p0 = fmaxf(a0.x + b.x, 0.f) * ww.x + fmaxf(a0.y + b.y, 0.f) * ww.y;
        float p1 = fmaxf(a1.x + b.x, 0.f) * ww.x + fmaxf(a1.y + b.y, 0.f) * ww.y;
        #pragma unroll
        for (int o = 32; o; o >>= 1) {
            p0 += __shfl_xor(p0, o);
            p1 += __shfl_xor(p1, o);
        }
        float w0 = 1.f / (1.f + expf(-(p0 + be)));
        float w1 = 1.f / (1.f + expf(-(p1 + be)));
        acc.x += w0 * h0.x + w1 * h1.x;
        acc.y += w0 * h0.y + w1 * h1.y;
    }
    if (j < e) {
        int s0 = ssrc[j];
        float2 a0 = ((const float2*)(A + (size_t)s0 * D))[lane];
        float2 h0 = ((const float2*)(h + (size_t)s0 * D))[lane];
        float p0 = fmaxf(a0.x + b.x, 0.f) * ww.x + fmaxf(a0.y + b.y, 0.f) * ww.y;
        p0 = wave_allsum(p0);
        float w0 = 1.f / (1.f + expf(-(p0 + be)));
        acc.x += w0 * h0.x;
        acc.y += w0 * h0.y;
    }
    ((float2*)(aggr + (size_t)node * D))[lane] = acc;
}

// gate + final LN, register-blocked f32
__global__ void __launch_bounds__(256) gate_v2(
    const float* __restrict__ h, const float* __restrict__ aggr,
    const float* __restrict__ WgTf, const float* __restrict__ bg,
    const float* __restrict__ g2, const float* __restrict__ bt2,
    float* __restrict__ out, int N)
{
    __shared__ float hs[NT][LDS_PAD];
    __shared__ float as[NT][LDS_PAD];
    __shared__ float ys[NT][LDS_PAD];
    const int t = threadIdx.x;
    const int col = t & 127;
    const int half = t >> 7;
    const int wid = t >> 6, lane = t & 63;
    const int base = blockIdx.x * NT;

    {
        int node = t >> 4, c0 = (t & 15) * 8;
        size_t g = (size_t)min(base + node, N - 1) * D + c0;
        const float4* hsrc = (const float4*)(h + g);
        const float4* asrc = (const float4*)(aggr + g);
        *(float4*)&hs[node][c0]     = hsrc[0];
        *(float4*)&hs[node][c0 + 4] = hsrc[1];
        *(float4*)&as[node][c0]     = asrc[0];
        *(float4*)&as[node][c0 + 4] = asrc[1];
    }
    __syncthreads();

    float acc[8];
    #pragma unroll
    for (int n = 0; n < 8; ++n) acc[n] = 0.f;
    {
        const float* wcol = WgTf + (size_t)col * 256;
        for (int k4 = 0; k4 < 32; ++k4) {
            float4 wt = *(const float4*)(wcol + k4 * 4);
            float4 wb = *(const float4*)(wcol + 128 + k4 * 4);
            #pragma unroll
            for (int n = 0; n < 8; ++n) {
                float4 hv = *(const float4*)&hs[half * 8 + n][k4 * 4];
                float4 av = *(const float4*)&as[half * 8 + n][k4 * 4];
                acc[n] += hv.x * wt.x + hv.y * wt.y + hv.z * wt.z + hv.w * wt.w
                        + av.x * wb.x + av.y * wb.y + av.z * wb.z + av.w * wb.w;
            }
        }
    }
    {
        float bgc = bg[col];
        #pragma unroll
        for (int n = 0; n < 8; ++n) {
            int node = half * 8 + n;
            float g = 1.f / (1.f + expf(-(acc[n] + bgc)));
            ys[node][col] = g * as[node][col] + (1.f - g) * hs[node][col];
        }
    }
    __syncthreads();

    {
        float gg0 = g2[2*lane], gg1 = g2[2*lane+1];
        float bb0 = bt2[2*lane], bb1 = bt2[2*lane+1];
        #pragma unroll
        for (int i = 0; i < 4; ++i) {
            int node = wid * 4 + i;
            float v0 = ys[node][2*lane], v1 = ys[node][2*lane+1];
            float s = wave_allsum(v0 + v1);
            float q = wave_allsum(v0*v0 + v1*v1);
            float m = s * (1.f/128.f);
            float var = q * (1.f/128.f) - m*m;
            float rs = rsqrtf(var + 1e-5f);
            if (base + node < N) {
                float2 o = make_float2((v0 - m)*rs*gg0 + bb0, (v1 - m)*rs*gg1 + bb1);
                *(float2*)&out[(size_t)(base + node) * D + 2*lane] = o;
            }
        }
    }
}

// ======================= diagnostic shadow path (subset grid) =======================

// err[0]=mfma vs direct dot (my C/D hyp); err[5]=mfma vs transposed hyp;
// err[1]=h; err[2]=A; err[3]=B
__global__ void __launch_bounds__(256) transform_mfma_check(
    const float* __restrict__ x,
    const unsigned short* __restrict__ W1Th, const unsigned short* __restrict__ W1Tl,
    const float* __restrict__ b1,
    const float* __restrict__ g1, const float* __restrict__ bt1,
    const unsigned short* __restrict__ We1Th, const unsigned short* __restrict__ We1Tl,
    const float* __restrict__ be1,
    const float* __restrict__ h, const float* __restrict__ A, const float* __restrict__ B,
    float* __restrict__ err, int N)
{
    __shared__ unsigned short xhi[16][LDH], xlo[16][LDH];
    __shared__ unsigned short hhi[16][LDH], hlo[16][LDH];
    __shared__ float yf[16][LDS_PAD];
    const int t = threadIdx.x;
    const int wid = t >> 6, lane = t & 63;
    const int base = blockIdx.x * 16;
    const int am = lane & 15;
    const int kb = (lane >> 4) * 8;
    const int n0 = wid * 32;

    {
        int node = t >> 4, c0 = (t & 15) * 8;
        int gn = min(base + node, N - 1);
        const float* src = x + (size_t)gn * D + c0;
        float v[8];
        float4 v0 = *(const float4*)src, v1 = *(const float4*)(src + 4);
        v[0]=v0.x; v[1]=v0.y; v[2]=v0.z; v[3]=v0.w;
        v[4]=v1.x; v[5]=v1.y; v[6]=v1.z; v[7]=v1.w;
        split_store8(v, &xhi[node][c0], &xlo[node][c0]);
    }
    __syncthreads();

    f32x4 acc0 = {0.f,0.f,0.f,0.f}, acc1 = {0.f,0.f,0.f,0.f};
    #pragma unroll
    for (int ks = 0; ks < 4; ++ks) {
        bf16x8 ah = *(const bf16x8*)&xhi[am][ks * 32 + kb];
        bf16x8 al = *(const bf16x8*)&xlo[am][ks * 32 + kb];
        size_t o0 = (size_t)(n0 + am) * 128 + ks * 32 + kb;
        size_t o1 = (size_t)(n0 + 16 + am) * 128 + ks * 32 + kb;
        bf16x8 bh0 = *(const bf16x8*)&W1Th[o0], bl0 = *(const bf16x8*)&W1Tl[o0];
        bf16x8 bh1 = *(const bf16x8*)&W1Th[o1], bl1 = *(const bf16x8*)&W1Tl[o1];
        MFMA3(acc0, ah, al, bh0, bl0);
        MFMA3(acc1, ah, al, bh1, bl1);
    }

    // direct-dot checks on acc0[0], both C/D layout hypotheses
    {
        int colA = n0 + am;              // my hyp: col=lane&15(+n0), row=(lane>>4)*4
        int rowA = (lane >> 4) * 4;
        int colT = n0 + (lane >> 4) * 4; // transposed hyp: row=lane&15, col=(lane>>4)*4(+n0)
        int rowT = am;
        float ref0 = 0.f, ref5 = 0.f;
        for (int k = 0; k < 128; ++k) {
            float xa = bf2f(xhi[rowA][k]) + bf2f(xlo[rowA][k]);
            float wa = bf2f(W1Th[(size_t)colA * 128 + k]) + bf2f(W1Tl[(size_t)colA * 128 + k]);
            ref0 += xa * wa;
            float xt = bf2f(xhi[rowT][k]) + bf2f(xlo[rowT][k]);
            float wt = bf2f(W1Th[(size_t)colT * 128 + k]) + bf2f(W1Tl[(size_t)colT * 128 + k]);
            ref5 += xt * wt;
        }
        float d0 = wave_allmax(fabsf(acc0[0] - ref0));
        float d5 = wave_allmax(fabsf(acc0[0] - ref5));
        if (lane == 0) { amax_err(&err[0], d0); amax_err(&err[5], d5); }
    }

    {
        float bia0 = b1[n0 + am], bia1 = b1[n0 + 16 + am];
        #pragma unroll
        for (int r = 0; r < 4; ++r) {
            int row = (lane >> 4) * 4 + r;
            yf[row][n0 + am]      = acc0[r] + bia0;
            yf[row][n0 + 16 + am] = acc1[r] + bia1;
        }
    }
    __syncthreads();

    {
        float gg0 = g1[2*lane], gg1 = g1[2*lane+1];
        float bb0 = bt1[2*lane], bb1 = bt1[2*lane+1];
        float dmax = 0.f;
        #pragma unroll
        for (int i = 0; i < 4; ++i) {
            int node = wid * 4 + i;
            float v0 = yf[node][2*lane], v1 = yf[node][2*lane+1];
            float s = wave_allsum(v0 + v1);
            float q = wave_allsum(v0*v0 + v1*v1);
            float m = s * (1.f/128.f);
            float var = q * (1.f/128.f) - m*m;
            float rs = rsqrtf(var + 1e-5f);
            float h0 = fmaxf((v0 - m)*rs*gg0 + bb0, 0.f);
            float h1 = fmaxf((v1 - m)*rs*gg1 + bb1, 0.f);
            unsigned short p0 = f2bf(h0), p1 = f2bf(h1);
            *(unsigned*)&hhi[node][2*lane] = (unsigned)p0 | ((unsigned)p1 << 16);
            *(unsigned*)&hlo[node][2*lane] =
                (unsigned)f2bf(h0 - bf2f(p0)) | ((unsigned)f2bf(h1 - bf2f(p1)) << 16);
            float2 hr = *(const float2*)&h[(size_t)(base + node) * D + 2*lane];
            dmax = fmaxf(dmax, fmaxf(fabsf(h0 - hr.x), fabsf(h1 - hr.y)));
        }
        float d = wave_allmax(dmax);
        if (lane == 0) amax_err(&err[1], d);
    }
    __syncthreads();

    f32x4 aA0 = {0.f,0.f,0.f,0.f}, aA1 = {0.f,0.f,0.f,0.f};
    f32x4 aB0 = {0.f,0.f,0.f,0.f}, aB1 = {0.f,0.f,0.f,0.f};
    #pragma unroll
    for (int ks = 0; ks < 4; ++ks) {
        bf16x8 ah = *(const bf16x8*)&hhi[am][ks * 32 + kb];
        bf16x8 al = *(const bf16x8*)&hlo[am][ks * 32 + kb];
        size_t t0 = (size_t)(n0 + am) * 256 + ks * 32 + kb;
        size_t t1 = (size_t)(n0 + 16 + am) * 256 + ks * 32 + kb;
        bf16x8 bth0 = *(const bf16x8*)&We1Th[t0], btl0 = *(const bf16x8*)&We1Tl[t0];
        bf16x8 bth1 = *(const bf16x8*)&We1Th[t1], btl1 = *(const bf16x8*)&We1Tl[t1];
        bf16x8 bbh0 = *(const bf16x8*)&We1Th[t0 + 128], bbl0 = *(const bf16x8*)&We1Tl[t0 + 128];
        bf16x8 bbh1 = *(const bf16x8*)&We1Th[t1 + 128], bbl1 = *(const bf16x8*)&We1Tl[t1 + 128];
        MFMA3(aA0, ah, al, bth0, btl0);
        MFMA3(aA1, ah, al, bth1, btl1);
        MFMA3(aB0, ah, al, bbh0, bbl0);
        MFMA3(aB1, ah, al, bbh1, bbl1);
    }
    {
        float beA0 = be1[n0 + am], beA1 = be1[n0 + 16 + am];
        float dA = 0.f, dB = 0.f;
        #pragma unroll
        for (int r = 0; r < 4; ++r) {
            int row = (lane >> 4) * 4 + r;
            int gn = base + row;
            size_t g0 = (size_t)gn * D + n0 + am;
            size_t g1i = (size_t)gn * D + n0 + 16 + am;
            dA = fmaxf(dA, fabsf(aA0[r] + beA0 - A[g0]));
            dA = fmaxf(dA, fabsf(aA1[r] + beA1 - A[g1i]));
            dB = fmaxf(dB, fabsf(aB0[r] - B[g0]));
            dB = fmaxf(dB, fabsf(aB1[r] - B[g1i]));
        }
        dA = wave_allmax(dA); dB = wave_allmax(dB);
        if (lane == 0) { amax_err(&err[2], dA); amax_err(&err[3], dB); }
    }
}

// err[4]: full MFMA gate path vs d_out
__global__ void __launch_bounds__(256) gate_mfma_check(
    const float* __restrict__ h, const float* __restrict__ aggr,
    const unsigned short* __restrict__ WgTh, const unsigned short* __restrict__ WgTl,
    const float* __restrict__ bg,
    const float* __restrict__ g2, const float* __restrict__ bt2,
    const float* __restrict__ out, float* __restrict__ err, int N)
{
    __shared__ unsigned short hhi[16][LDH], hlo[16][LDH];
    __shared__ unsigned short ahi[16][LDH], alo[16][LDH];
    __shared__ float yf[16][LDS_PAD];
    const int t = threadIdx.x;
    const int wid = t >> 6, lane = t & 63;
    const int base = blockIdx.x * 16;
    const int am = lane & 15;
    const int kb = (lane >> 4) * 8;
    const int n0 = wid * 32;

    {
        int node = t >> 4, c0 = (t & 15) * 8;
        size_t g = (size_t)min(base + node, N - 1) * D + c0;
        float v[8];
        float4 u0 = *(const float4*)&h[g], u1 = *(const float4*)&h[g + 4];
        v[0]=u0.x; v[1]=u0.y; v[2]=u0.z; v[3]=u0.w;
        v[4]=u1.x; v[5]=u1.y; v[6]=u1.z; v[7]=u1.w;
        split_store8(v, &hhi[node][c0], &hlo[node][c0]);
        float4 a0 = *(const float4*)&aggr[g], a1 = *(const float4*)&aggr[g + 4];
        v[0]=a0.x; v[1]=a0.y; v[2]=a0.z; v[3]=a0.w;
        v[4]=a1.x; v[5]=a1.y; v[6]=a1.z; v[7]=a1.w;
        split_store8(v, &ahi[node][c0], &alo[node][c0]);
    }
    __syncthreads();

    f32x4 acc0 = {0.f,0.f,0.f,0.f}, acc1 = {0.f,0.f,0.f,0.f};
    #pragma unroll
    for (int ks = 0; ks < 4; ++ks) {
        size_t o0 = (size_t)(n0 + am) * 256 + ks * 32 + kb;
        size_t o1 = (size_t)(n0 + 16 + am) * 256 + ks * 32 + kb;
        {
            bf16x8 ah = *(const bf16x8*)&hhi[am][ks * 32 + kb];
            bf16x8 al = *(const bf16x8*)&hlo[am][ks * 32 + kb];
            bf16x8 bh0 = *(const bf16x8*)&WgTh[o0], bl0 = *(const bf16x8*)&WgTl[o0];
            bf16x8 bh1 = *(const bf16x8*)&WgTh[o1], bl1 = *(const bf16x8*)&WgTl[o1];
            MFMA3(acc0, ah, al, bh0, bl0);
            MFMA3(acc1, ah, al, bh1, bl1);
        }
        {
            bf16x8 ah = *(const bf16x8*)&ahi[am][ks * 32 + kb];
            bf16x8 al = *(const bf16x8*)&alo[am][ks * 32 + kb];
            bf16x8 bh0 = *(const bf16x8*)&WgTh[o0 + 128], bl0 = *(const bf16x8*)&WgTl[o0 + 128];
            bf16x8 bh1 = *(const bf16x8*)&WgTh[o1 + 128], bl1 = *(const bf16x8*)&WgTl[o1 + 128];
            MFMA3(acc0, ah, al, bh0, bl0);
            MFMA3(acc1, ah, al, bh1, bl1);
        }
    }
    {
        float bg0 = bg[n0 + am], bg1 = bg[n0 + 16 + am];
        #pragma unroll
        for (int r = 0; r < 4; ++r) {
            int row = (lane >> 4) * 4 + r;
            int c0 = n0 + am, c1 = n0 + 16 + am;
            float g0 = 1.f / (1.f + expf(-(acc0[r] + bg0)));
            float g1v= 1.f / (1.f + expf(-(acc1[r] + bg1)));
            float hv0 = bf2f(hhi[row][c0]) + bf2f(hlo[row][c0]);
            float av0 = bf2f(ahi[row][c0]) + bf2f(alo[row][c0]);
            float hv1 = bf2f(hhi[row][c1]) + bf2f(hlo[row][c1]);
            float av1 = bf2f(ahi[row][c1]) + bf2f(alo[row][c1]);
            yf[row][c0] = g0 * av0 + (1.f - g0) * hv0;
            yf[row][c1] = g1v * av1 + (1.f - g1v) * hv1;
        }
    }
    __syncthreads();

    {
        float gg0 = g2[2*lane], gg1 = g2[2*lane+1];
        float bb0 = bt2[2*lane], bb1 = bt2[2*lane+1];
        float dmax = 0.f;
        #pragma unroll
        for (int i = 0; i < 4; ++i) {
            int node = wid * 4 + i;
            float v0 = yf[node][2*lane], v1 = yf[node][2*lane+1];
            float s = wave_allsum(v0 + v1);
            float q = wave_allsum(v0*v0 + v1*v1);
            float m = s * (1.f/128.f);
            float var = q * (1.f/128.f) - m*m;
            float rs = rsqrtf(var + 1e-5f);
            float o0 = (v0 - m)*rs*gg0 + bb0;
            float o1 = (v1 - m)*rs*gg1 + bb1;
            float2 orf = *(const float2*)&out[(size_t)(base + node) * D + 2*lane];
            dmax = fmaxf(dmax, fmaxf(fabsf(o0 - orf.x), fabsf(o1 - orf.y)));
        }
        float d = wave_allmax(dmax);
        if (lane == 0) amax_err(&err[4], d);
    }
}

__device__ __forceinline__ void spin_if(int cond, long long cyc) {
    if (cond) {
        long long t0 = clock64();
        while (clock64() - t0 < cyc) __builtin_amdgcn_s_sleep(8);
    }
}
__global__ void diag_y_bad(const float* err)   { spin_if(err[0] > 0.01f,  3000000LL); }
__global__ void diag_h_bad(const float* err)   { spin_if(err[1] > 0.01f,  6000000LL); }
__global__ void diag_A_bad(const float* err)   { spin_if(err[2] > 0.01f,  9000000LL); }
__global__ void diag_B_bad(const float* err)   { spin_if(err[3] > 0.01f, 12000000LL); }
__global__ void diag_out_bad(const float* err) { spin_if(err[4] > 0.05f, 15000000LL); }
__global__ void diag_yT(const float* err)      { spin_if(err[0] > 0.01f && err[5] <= 0.01f, 18000000LL); }

extern "C" void kernel_launch(void* const* d_in, const int* in_sizes, int n_in,
                              void* d_out, int out_size, void* d_ws, size_t ws_size,
                              hipStream_t stream) {
    const float* x   = (const float*)d_in[0];
    const int*   ei  = (const int*)d_in[1];
    const float* W1  = (const float*)d_in[2];
    const float* b1  = (const float*)d_in[3];
    const float* g1  = (const float*)d_in[4];
    const float* bt1 = (const float*)d_in[5];
    const float* We1 = (const float*)d_in[6];
    const float* be1 = (const float*)d_in[7];
    const float* We2 = (const float*)d_in[8];
    const float* be2 = (const float*)d_in[9];
    const float* Wg  = (const float*)d_in[14];
    const float* bg  = (const float*)d_in[15];
    const float* g2  = (const float*)d_in[16];
    const float* bt2 = (const float*)d_in[17];

    const int N = in_sizes[0] / D;
    const int E = in_sizes[1] / 2;
    const size_t ND = (size_t)N * D;

    float* h    = (float*)d_ws;
    float* A    = h + ND;
    float* B    = A + ND;
    float* aggr = B + ND;
    float* W1Tf  = aggr + ND;
    float* We1Tf = W1Tf + 16384;
    float* WgTf  = We1Tf + 32768;
    unsigned short* W1Th  = (unsigned short*)(WgTf + 32768);
    unsigned short* W1Tl  = W1Th + 16384;
    unsigned short* We1Th = W1Tl + 16384;
    unsigned short* We1Tl = We1Th + 32768;
    unsigned short* WgTh  = We1Tl + 32768;
    unsigned short* WgTl  = WgTh + 32768;
    int* deg    = (int*)(WgTl + 32768);
    int* off    = deg + (N + 1);
    int* cursor = off + (N + 1);
    int* ssrc   = cursor + (N + 1);
    float* err  = (float*)(ssrc + E);

    (void)hipMemsetAsync(deg, 0, (size_t)(N + 1) * sizeof(int), stream);
    (void)hipMemsetAsync(err, 0, 8 * sizeof(float), stream);

    prep_wf32<<<320, 256, 0, stream>>>(W1, We1, Wg, W1Tf, We1Tf, WgTf);
    prep_wbf<<<320, 256, 0, stream>>>(W1, We1, Wg, W1Th, W1Tl, We1Th, We1Tl, WgTh, WgTl);
    hist_kernel<<<(E + 255) / 256, 256, 0, stream>>>(ei, deg, E);
    scan_kernel<<<1, 1024, 0, stream>>>(deg, off, cursor, N);
    scatter_kernel<<<(E + 255) / 256, 256, 0, stream>>>(ei, cursor, ssrc, E);

    const int nblk = (N + NT - 1) / NT;
    transform_v2<<<nblk, 256, 0, stream>>>(x, W1Tf, b1, g1, bt1, We1Tf, be1, h, A, B, N);
    agg_v2<<<(N + 3) / 4, 256, 0, stream>>>(off, ssrc, A, B, We2, be2, h, aggr, N);
    gate_v2<<<nblk, 256, 0, stream>>>(h, aggr, WgTf, bg, g2, bt2, (float*)d_out, N);

    // shadow diagnostics on a 64-block subset (nodes 0..1023), read-only
    transform_mfma_check<<<64, 256, 0, stream>>>(x, W1Th, W1Tl, b1, g1, bt1,
                                                 We1Th, We1Tl, be1, h, A, B, err, N);
    gate_mfma_check<<<64, 256, 0, stream>>>(h, aggr, WgTh, WgTl, bg, g2, bt2,
                                            (const float*)d_out, err, N);
    diag_y_bad<<<1, 64, 0, stream>>>(err);
    diag_h_bad<<<1, 64, 0, stream>>>(err);
    diag_A_bad<<<1, 64, 0, stream>>>(err);
    diag_B_bad<<<1, 64, 0, stream>>>(err);
    diag_out_bad<<<1, 64, 0, stream>>>(err);
    diag_yT<<<1, 64, 0, stream>>>(err);
}

// Round 9
// 521.137 us; speedup vs baseline: 2.6402x; 1.3204x over previous
//
#include <hip/hip_runtime.h>
#include <math.h>

#define D 128
#define NT 16
#define LP 132   // padded f32 LDS row

__device__ __forceinline__ float wave_allsum(float v) {
    #pragma unroll
    for (int off = 32; off; off >>= 1) v += __shfl_xor(v, off);
    return v;
}

// ======================= transform: h=relu(LN(x@W1+b1)); A=h@We1_top+be1; B=h@We1_bot
// 16 nodes/block, 256 threads. Wave q owns nodes q*4..q*4+3; lane owns cols c and c+64.
__global__ void __launch_bounds__(256) transform_v3(
    const float* __restrict__ x, const float* __restrict__ W1, const float* __restrict__ b1,
    const float* __restrict__ g1, const float* __restrict__ bt1,
    const float* __restrict__ We1, const float* __restrict__ be1,
    float* __restrict__ h, float* __restrict__ A, float* __restrict__ B, int N)
{
    __shared__ float xs[NT][LP];
    __shared__ float ys[NT][LP];
    const int t = threadIdx.x;
    const int q = t >> 6, lane = t & 63;
    const int c = lane;
    const int base = blockIdx.x * NT;

    // stage x
    {
        int node = t >> 4, c0 = (t & 15) * 8;
        int gn = min(base + node, N - 1);
        const float4* src = (const float4*)(x + (size_t)gn * D + c0);
        *(float4*)&xs[node][c0]     = src[0];
        *(float4*)&xs[node][c0 + 4] = src[1];
    }
    __syncthreads();

    // GEMM1: y = x@W1  (native [k][n] weights, coalesced)
    float acc[4][2];
    #pragma unroll
    for (int n = 0; n < 4; ++n) { acc[n][0] = 0.f; acc[n][1] = 0.f; }
    for (int k = 0; k < 128; k += 4) {
        float w00 = W1[(k+0)*128 + c],      w01 = W1[(k+0)*128 + c + 64];
        float w10 = W1[(k+1)*128 + c],      w11 = W1[(k+1)*128 + c + 64];
        float w20 = W1[(k+2)*128 + c],      w21 = W1[(k+2)*128 + c + 64];
        float w30 = W1[(k+3)*128 + c],      w31 = W1[(k+3)*128 + c + 64];
        #pragma unroll
        for (int n = 0; n < 4; ++n) {
            float4 xv = *(const float4*)&xs[q*4+n][k];
            acc[n][0] += xv.x*w00 + xv.y*w10 + xv.z*w20 + xv.w*w30;
            acc[n][1] += xv.x*w01 + xv.y*w11 + xv.z*w21 + xv.w*w31;
        }
    }
    {
        float b0 = b1[c], b1v = b1[c + 64];
        #pragma unroll
        for (int n = 0; n < 4; ++n) {
            ys[q*4+n][c]      = acc[n][0] + b0;
            ys[q*4+n][c + 64] = acc[n][1] + b1v;
        }
    }
    __syncthreads();

    // LN + relu (wave q handles its own 4 nodes); h -> global + xs (reused)
    {
        float gg0 = g1[2*lane], gg1 = g1[2*lane+1];
        float bb0 = bt1[2*lane], bb1 = bt1[2*lane+1];
        #pragma unroll
        for (int i = 0; i < 4; ++i) {
            int node = q * 4 + i;
            float v0 = ys[node][2*lane], v1 = ys[node][2*lane+1];
            float s = wave_allsum(v0 + v1);
            float qq = wave_allsum(v0*v0 + v1*v1);
            float m = s * (1.f/128.f);
            float var = qq * (1.f/128.f) - m*m;
            float rs = rsqrtf(var + 1e-5f);
            float h0 = fmaxf((v0 - m)*rs*gg0 + bb0, 0.f);
            float h1 = fmaxf((v1 - m)*rs*gg1 + bb1, 0.f);
            *(float2*)&xs[node][2*lane] = make_float2(h0, h1);
            if (base + node < N)
                *(float2*)&h[(size_t)(base + node) * D + 2*lane] = make_float2(h0, h1);
        }
    }
    __syncthreads();

    // GEMM2: A = h@We1[0:128,:] + be1 ; B = h@We1[128:256,:]
    float aA[4][2], aB[4][2];
    #pragma unroll
    for (int n = 0; n < 4; ++n) { aA[n][0]=0.f; aA[n][1]=0.f; aB[n][0]=0.f; aB[n][1]=0.f; }
    for (int k = 0; k < 128; k += 4) {
        float t00 = We1[(k+0)*128 + c],       t01 = We1[(k+0)*128 + c + 64];
        float t10 = We1[(k+1)*128 + c],       t11 = We1[(k+1)*128 + c + 64];
        float t20 = We1[(k+2)*128 + c],       t21 = We1[(k+2)*128 + c + 64];
        float t30 = We1[(k+3)*128 + c],       t31 = We1[(k+3)*128 + c + 64];
        float u00 = We1[(k+128)*128 + c],     u01 = We1[(k+128)*128 + c + 64];
        float u10 = We1[(k+129)*128 + c],     u11 = We1[(k+129)*128 + c + 64];
        float u20 = We1[(k+130)*128 + c],     u21 = We1[(k+130)*128 + c + 64];
        float u30 = We1[(k+131)*128 + c],     u31 = We1[(k+131)*128 + c + 64];
        #pragma unroll
        for (int n = 0; n < 4; ++n) {
            float4 hv = *(const float4*)&xs[q*4+n][k];
            aA[n][0] += hv.x*t00 + hv.y*t10 + hv.z*t20 + hv.w*t30;
            aA[n][1] += hv.x*t01 + hv.y*t11 + hv.z*t21 + hv.w*t31;
            aB[n][0] += hv.x*u00 + hv.y*u10 + hv.z*u20 + hv.w*u30;
            aB[n][1] += hv.x*u01 + hv.y*u11 + hv.z*u21 + hv.w*u31;
        }
    }
    {
        float be0 = be1[c], be1v = be1[c + 64];
        #pragma unroll
        for (int n = 0; n < 4; ++n) {
            int gn = base + q*4 + n;
            if (gn < N) {
                A[(size_t)gn * D + c]      = aA[n][0] + be0;
                A[(size_t)gn * D + c + 64] = aA[n][1] + be1v;
                B[(size_t)gn * D + c]      = aB[n][0];
                B[(size_t)gn * D + c + 64] = aB[n][1];
            }
        }
    }
}

// ---- CSR build ----
__global__ void __launch_bounds__(256) hist_kernel(const int* __restrict__ ei,
                                                   int* __restrict__ deg, int E) {
    int e = blockIdx.x * 256 + threadIdx.x;
    if (e < E) atomicAdd(&deg[ei[E + e]], 1);
}

__global__ void __launch_bounds__(1024) scan_kernel(const int* __restrict__ deg,
                                                    int* __restrict__ off,
                                                    int* __restrict__ cursor, int N) {
    __shared__ int partial[1024];
    const int t = threadIdx.x;
    const int chunk = (N + 1023) / 1024;
    const int start = t * chunk;
    const int end = min(start + chunk, N);
    int s = 0;
    for (int i = start; i < end; ++i) s += deg[i];
    partial[t] = s;
    __syncthreads();
    for (int d = 1; d < 1024; d <<= 1) {
        int v = (t >= d) ? partial[t - d] : 0;
        __syncthreads();
        if (t >= d) partial[t] += v;
        __syncthreads();
    }
    int run = (t == 0) ? 0 : partial[t - 1];
    for (int i = start; i < end; ++i) {
        off[i] = run;
        cursor[i] = run;
        run += deg[i];
    }
    if (t == 0) off[N] = partial[1023];
}

__global__ void __launch_bounds__(256) scatter_kernel(const int* __restrict__ ei,
                                                      int* __restrict__ cursor,
                                                      int* __restrict__ ssrc, int E) {
    int e = blockIdx.x * 256 + threadIdx.x;
    if (e < E) {
        int pos = atomicAdd(&cursor[ei[E + e]], 1);
        ssrc[pos] = ei[e];
    }
}

// ======================= pull aggregation: wave per node, 16 lanes per edge, 4 edges in flight
__global__ void __launch_bounds__(256) agg_v4(
    const int* __restrict__ off, const int* __restrict__ ssrc,
    const float* __restrict__ A, const float* __restrict__ B,
    const float* __restrict__ We2, const float* __restrict__ be2,
    const float* __restrict__ h, float* __restrict__ aggr, int N)
{
    const int wid = threadIdx.x >> 6, lane = threadIdx.x & 63;
    const int node = blockIdx.x * 4 + wid;
    if (node >= N) return;
    const int g = lane >> 4;          // edge sub-group 0..3
    const int c8 = (lane & 15) * 8;   // 8 cols owned by this lane within its group

    const float4* Bp = (const float4*)(B + (size_t)node * D + c8);
    float4 b0 = Bp[0], b1 = Bp[1];
    const float4* Wp = (const float4*)(We2 + c8);
    float4 w0 = Wp[0], w1 = Wp[1];
    const float be = be2[0];

    float4 acc0 = make_float4(0.f,0.f,0.f,0.f);
    float4 acc1 = make_float4(0.f,0.f,0.f,0.f);

    const int s = off[node], e = off[node + 1];
    const int nit = (e - s + 3) >> 2;
    for (int it = 0; it < nit; ++it) {
        int j = s + it * 4 + g;
        bool valid = (j < e);
        int src = valid ? ssrc[j] : ssrc[s];
        const float4* Ap = (const float4*)(A + (size_t)src * D + c8);
        float4 a0 = Ap[0], a1 = Ap[1];
        const float4* Hp = (const float4*)(h + (size_t)src * D + c8);
        float4 h0 = Hp[0], h1 = Hp[1];
        float d = fmaxf(a0.x + b0.x, 0.f) * w0.x + fmaxf(a0.y + b0.y, 0.f) * w0.y
                + fmaxf(a0.z + b0.z, 0.f) * w0.z + fmaxf(a0.w + b0.w, 0.f) * w0.w
                + fmaxf(a1.x + b1.x, 0.f) * w1.x + fmaxf(a1.y + b1.y, 0.f) * w1.y
                + fmaxf(a1.z + b1.z, 0.f) * w1.z + fmaxf(a1.w + b1.w, 0.f) * w1.w;
        d += __shfl_xor(d, 1);
        d += __shfl_xor(d, 2);
        d += __shfl_xor(d, 4);
        d += __shfl_xor(d, 8);
        float wgt = valid ? 1.f / (1.f + expf(-(d + be))) : 0.f;
        acc0.x += wgt * h0.x; acc0.y += wgt * h0.y; acc0.z += wgt * h0.z; acc0.w += wgt * h0.w;
        acc1.x += wgt * h1.x; acc1.y += wgt * h1.y; acc1.z += wgt * h1.z; acc1.w += wgt * h1.w;
    }

    // combine the 4 sub-group partials (cols identical across groups)
    #pragma unroll
    for (int o = 16; o <= 32; o <<= 1) {
        acc0.x += __shfl_xor(acc0.x, o); acc0.y += __shfl_xor(acc0.y, o);
        acc0.z += __shfl_xor(acc0.z, o); acc0.w += __shfl_xor(acc0.w, o);
        acc1.x += __shfl_xor(acc1.x, o); acc1.y += __shfl_xor(acc1.y, o);
        acc1.z += __shfl_xor(acc1.z, o); acc1.w += __shfl_xor(acc1.w, o);
    }
    if (g == 0) {
        float4* Op = (float4*)(aggr + (size_t)node * D + c8);
        Op[0] = acc0;
        Op[1] = acc1;
    }
}

// ======================= gate + final LN
__global__ void __launch_bounds__(256) gate_v3(
    const float* __restrict__ h, const float* __restrict__ aggr,
    const float* __restrict__ Wg, const float* __restrict__ bg,
    const float* __restrict__ g2, const float* __restrict__ bt2,
    float* __restrict__ out, int N)
{
    __shared__ float hs[NT][LP];
    __shared__ float as[NT][LP];
    __shared__ float ys[NT][LP];
    const int t = threadIdx.x;
    const int q = t >> 6, lane = t & 63;
    const int c = lane;
    const int base = blockIdx.x * NT;

    {
        int node = t >> 4, c0 = (t & 15) * 8;
        size_t g = (size_t)min(base + node, N - 1) * D + c0;
        const float4* hsrc = (const float4*)(h + g);
        const float4* asrc = (const float4*)(aggr + g);
        *(float4*)&hs[node][c0]     = hsrc[0];
        *(float4*)&hs[node][c0 + 4] = hsrc[1];
        *(float4*)&as[node][c0]     = asrc[0];
        *(float4*)&as[node][c0 + 4] = asrc[1];
    }
    __syncthreads();

    // gate pre-activation: h@Wg[0:128,:] + aggr@Wg[128:256,:]
    float acc[4][2];
    #pragma unroll
    for (int n = 0; n < 4; ++n) { acc[n][0] = 0.f; acc[n][1] = 0.f; }
    for (int k = 0; k < 128; k += 4) {
        float t00 = Wg[(k+0)*128 + c],    t01 = Wg[(k+0)*128 + c + 64];
        float t10 = Wg[(k+1)*128 + c],    t11 = Wg[(k+1)*128 + c + 64];
        float t20 = Wg[(k+2)*128 + c],    t21 = Wg[(k+2)*128 + c + 64];
        float t30 = Wg[(k+3)*128 + c],    t31 = Wg[(k+3)*128 + c + 64];
        float u00 = Wg[(k+128)*128 + c],  u01 = Wg[(k+128)*128 + c + 64];
        float u10 = Wg[(k+129)*128 + c],  u11 = Wg[(k+129)*128 + c + 64];
        float u20 = Wg[(k+130)*128 + c],  u21 = Wg[(k+130)*128 + c + 64];
        float u30 = Wg[(k+131)*128 + c],  u31 = Wg[(k+131)*128 + c + 64];
        #pragma unroll
        for (int n = 0; n < 4; ++n) {
            float4 hv = *(const float4*)&hs[q*4+n][k];
            float4 av = *(const float4*)&as[q*4+n][k];
            acc[n][0] += hv.x*t00 + hv.y*t10 + hv.z*t20 + hv.w*t30
                       + av.x*u00 + av.y*u10 + av.z*u20 + av.w*u30;
            acc[n][1] += hv.x*t01 + hv.y*t11 + hv.z*t21 + hv.w*t31
                       + av.x*u01 + av.y*u11 + av.z*u21 + av.w*u31;
        }
    }
    {
        float bg0 = bg[c], bg1 = bg[c + 64];
        #pragma unroll
        for (int n = 0; n < 4; ++n) {
            int node = q*4 + n;
            float ga = 1.f / (1.f + expf(-(acc[n][0] + bg0)));
            float gb = 1.f / (1.f + expf(-(acc[n][1] + bg1)));
            ys[node][c]      = ga * as[node][c]      + (1.f - ga) * hs[node][c];
            ys[node][c + 64] = gb * as[node][c + 64] + (1.f - gb) * hs[node][c + 64];
        }
    }
    __syncthreads();

    {
        float gg0 = g2[2*lane], gg1 = g2[2*lane+1];
        float bb0 = bt2[2*lane], bb1 = bt2[2*lane+1];
        #pragma unroll
        for (int i = 0; i < 4; ++i) {
            int node = q * 4 + i;
            float v0 = ys[node][2*lane], v1 = ys[node][2*lane+1];
            float s = wave_allsum(v0 + v1);
            float qq = wave_allsum(v0*v0 + v1*v1);
            float m = s * (1.f/128.f);
            float var = qq * (1.f/128.f) - m*m;
            float rs = rsqrtf(var + 1e-5f);
            if (base + node < N) {
                float2 o = make_float2((v0 - m)*rs*gg0 + bb0, (v1 - m)*rs*gg1 + bb1);
                *(float2*)&out[(size_t)(base + node) * D + 2*lane] = o;
            }
        }
    }
}

extern "C" void kernel_launch(void* const* d_in, const int* in_sizes, int n_in,
                              void* d_out, int out_size, void* d_ws, size_t ws_size,
                              hipStream_t stream) {
    const float* x   = (const float*)d_in[0];
    const int*   ei  = (const int*)d_in[1];
    const float* W1  = (const float*)d_in[2];
    const float* b1  = (const float*)d_in[3];
    const float* g1  = (const float*)d_in[4];
    const float* bt1 = (const float*)d_in[5];
    const float* We1 = (const float*)d_in[6];
    const float* be1 = (const float*)d_in[7];
    const float* We2 = (const float*)d_in[8];
    const float* be2 = (const float*)d_in[9];
    const float* Wg  = (const float*)d_in[14];
    const float* bg  = (const float*)d_in[15];
    const float* g2  = (const float*)d_in[16];
    const float* bt2 = (const float*)d_in[17];

    const int N = in_sizes[0] / D;
    const int E = in_sizes[1] / 2;
    const size_t ND = (size_t)N * D;

    float* h    = (float*)d_ws;
    float* A    = h + ND;
    float* B    = A + ND;
    float* aggr = B + ND;
    int* deg    = (int*)(aggr + ND);
    int* off    = deg + (N + 1);
    int* cursor = off + (N + 1);
    int* ssrc   = cursor + (N + 1);

    (void)hipMemsetAsync(deg, 0, (size_t)(N + 1) * sizeof(int), stream);

    hist_kernel<<<(E + 255) / 256, 256, 0, stream>>>(ei, deg, E);
    scan_kernel<<<1, 1024, 0, stream>>>(deg, off, cursor, N);
    scatter_kernel<<<(E + 255) / 256, 256, 0, stream>>>(ei, cursor, ssrc, E);

    const int nblk = (N + NT - 1) / NT;
    transform_v3<<<nblk, 256, 0, stream>>>(x, W1, b1, g1, bt1, We1, be1, h, A, B, N);
    agg_v4<<<(N + 3) / 4, 256, 0, stream>>>(off, ssrc, A, B, We2, be2, h, aggr, N);
    gate_v3<<<nblk, 256, 0, stream>>>(h, aggr, Wg, bg, g2, bt2, (float*)d_out, N);
}

// Round 10
// 403.120 us; speedup vs baseline: 3.4132x; 1.2928x over previous
//
#include <hip/hip_runtime.h>
#include <math.h>

#define D 128
#define NT 32
#define LP 132   // padded f32 LDS row

__device__ __forceinline__ float wave_allsum(float v) {
    #pragma unroll
    for (int off = 32; off; off >>= 1) v += __shfl_xor(v, off);
    return v;
}

// ======================= transform: h=relu(LN(x@W1+b1)); A=h@We1_top+be1; B=h@We1_bot
// 32 nodes/block, 256 threads. Wave q owns nodes q*8..q*8+7; lane owns cols c and c+64.
__global__ void __launch_bounds__(256) transform_v4(
    const float* __restrict__ x, const float* __restrict__ W1, const float* __restrict__ b1,
    const float* __restrict__ g1, const float* __restrict__ bt1,
    const float* __restrict__ We1, const float* __restrict__ be1,
    float* __restrict__ h, float* __restrict__ A, float* __restrict__ B, int N)
{
    __shared__ float xs[NT][LP];
    __shared__ float ys[NT][LP];
    const int t = threadIdx.x;
    const int q = t >> 6, lane = t & 63;
    const int c = lane;
    const int base = blockIdx.x * NT;

    // stage x: thread t -> node t>>3, 16 cols at (t&7)*16
    {
        int node = t >> 3, c0 = (t & 7) * 16;
        int gn = min(base + node, N - 1);
        const float4* src = (const float4*)(x + (size_t)gn * D + c0);
        float4* dst = (float4*)&xs[node][c0];
        dst[0] = src[0]; dst[1] = src[1]; dst[2] = src[2]; dst[3] = src[3];
    }
    __syncthreads();

    // GEMM1: y = x@W1  (native [k][n] weights, coalesced)
    float acc[8][2];
    #pragma unroll
    for (int n = 0; n < 8; ++n) { acc[n][0] = 0.f; acc[n][1] = 0.f; }
    for (int k = 0; k < 128; k += 4) {
        float w00 = W1[(k+0)*128 + c],      w01 = W1[(k+0)*128 + c + 64];
        float w10 = W1[(k+1)*128 + c],      w11 = W1[(k+1)*128 + c + 64];
        float w20 = W1[(k+2)*128 + c],      w21 = W1[(k+2)*128 + c + 64];
        float w30 = W1[(k+3)*128 + c],      w31 = W1[(k+3)*128 + c + 64];
        #pragma unroll
        for (int n = 0; n < 8; ++n) {
            float4 xv = *(const float4*)&xs[q*8+n][k];
            acc[n][0] += xv.x*w00 + xv.y*w10 + xv.z*w20 + xv.w*w30;
            acc[n][1] += xv.x*w01 + xv.y*w11 + xv.z*w21 + xv.w*w31;
        }
    }
    {
        float b0 = b1[c], b1v = b1[c + 64];
        #pragma unroll
        for (int n = 0; n < 8; ++n) {
            ys[q*8+n][c]      = acc[n][0] + b0;
            ys[q*8+n][c + 64] = acc[n][1] + b1v;
        }
    }
    __syncthreads();

    // LN + relu (wave q handles its own 8 nodes); h -> global + xs (reused)
    {
        float gg0 = g1[2*lane], gg1 = g1[2*lane+1];
        float bb0 = bt1[2*lane], bb1 = bt1[2*lane+1];
        #pragma unroll
        for (int i = 0; i < 8; ++i) {
            int node = q * 8 + i;
            float v0 = ys[node][2*lane], v1 = ys[node][2*lane+1];
            float s = wave_allsum(v0 + v1);
            float qq = wave_allsum(v0*v0 + v1*v1);
            float m = s * (1.f/128.f);
            float var = qq * (1.f/128.f) - m*m;
            float rs = rsqrtf(var + 1e-5f);
            float h0 = fmaxf((v0 - m)*rs*gg0 + bb0, 0.f);
            float h1 = fmaxf((v1 - m)*rs*gg1 + bb1, 0.f);
            *(float2*)&xs[node][2*lane] = make_float2(h0, h1);
            if (base + node < N)
                *(float2*)&h[(size_t)(base + node) * D + 2*lane] = make_float2(h0, h1);
        }
    }
    __syncthreads();

    // GEMM2: A = h@We1[0:128,:] + be1 ; B = h@We1[128:256,:]
    float aA[8][2], aB[8][2];
    #pragma unroll
    for (int n = 0; n < 8; ++n) { aA[n][0]=0.f; aA[n][1]=0.f; aB[n][0]=0.f; aB[n][1]=0.f; }
    for (int k = 0; k < 128; k += 4) {
        float t00 = We1[(k+0)*128 + c],       t01 = We1[(k+0)*128 + c + 64];
        float t10 = We1[(k+1)*128 + c],       t11 = We1[(k+1)*128 + c + 64];
        float t20 = We1[(k+2)*128 + c],       t21 = We1[(k+2)*128 + c + 64];
        float t30 = We1[(k+3)*128 + c],       t31 = We1[(k+3)*128 + c + 64];
        float u00 = We1[(k+128)*128 + c],     u01 = We1[(k+128)*128 + c + 64];
        float u10 = We1[(k+129)*128 + c],     u11 = We1[(k+129)*128 + c + 64];
        float u20 = We1[(k+130)*128 + c],     u21 = We1[(k+130)*128 + c + 64];
        float u30 = We1[(k+131)*128 + c],     u31 = We1[(k+131)*128 + c + 64];
        #pragma unroll
        for (int n = 0; n < 8; ++n) {
            float4 hv = *(const float4*)&xs[q*8+n][k];
            aA[n][0] += hv.x*t00 + hv.y*t10 + hv.z*t20 + hv.w*t30;
            aA[n][1] += hv.x*t01 + hv.y*t11 + hv.z*t21 + hv.w*t31;
            aB[n][0] += hv.x*u00 + hv.y*u10 + hv.z*u20 + hv.w*u30;
            aB[n][1] += hv.x*u01 + hv.y*u11 + hv.z*u21 + hv.w*u31;
        }
    }
    {
        float be0 = be1[c], be1v = be1[c + 64];
        #pragma unroll
        for (int n = 0; n < 8; ++n) {
            int gn = base + q*8 + n;
            if (gn < N) {
                A[(size_t)gn * D + c]      = aA[n][0] + be0;
                A[(size_t)gn * D + c + 64] = aA[n][1] + be1v;
                B[(size_t)gn * D + c]      = aB[n][0];
                B[(size_t)gn * D + c + 64] = aB[n][1];
            }
        }
    }
}

// ---- CSR build ----
__global__ void __launch_bounds__(256) hist_kernel(const int* __restrict__ ei,
                                                   int* __restrict__ deg, int E) {
    int e = blockIdx.x * 256 + threadIdx.x;
    if (e < E) atomicAdd(&deg[ei[E + e]], 1);
}

#define SCB 64   // scan blocks

// phase a: block b sums its chunk of deg -> bsum[b]
__global__ void __launch_bounds__(256) scan_a(const int* __restrict__ deg,
                                              int* __restrict__ bsum, int N) {
    __shared__ int red[256];
    const int b = blockIdx.x, t = threadIdx.x;
    const int C = (N + SCB - 1) / SCB;
    const int W = (C + 255) / 256;
    int s0 = b * C + t * W;
    int s1 = min(s0 + W, min((b + 1) * C, N));
    int s = 0;
    for (int i = s0; i < s1; ++i) s += deg[i];
    red[t] = s;
    __syncthreads();
    #pragma unroll
    for (int d = 128; d; d >>= 1) {
        if (t < d) red[t] += red[t + d];
        __syncthreads();
    }
    if (t == 0) bsum[b] = red[0];
}

// phase b: 1 block, exclusive prefix of bsum -> boff; off[N] = total
__global__ void __launch_bounds__(64) scan_b(const int* __restrict__ bsum,
                                             int* __restrict__ boff,
                                             int* __restrict__ off, int N) {
    const int t = threadIdx.x;
    __shared__ int v[SCB];
    v[t] = bsum[t];
    __syncthreads();
    if (t == 0) {
        int run = 0;
        for (int i = 0; i < SCB; ++i) { boff[i] = run; run += v[i]; }
        off[N] = run;
    }
}

// phase c: block b writes off/cursor for its chunk
__global__ void __launch_bounds__(256) scan_c(const int* __restrict__ deg,
                                              const int* __restrict__ boff,
                                              int* __restrict__ off,
                                              int* __restrict__ cursor, int N) {
    __shared__ int pre[256];
    const int b = blockIdx.x, t = threadIdx.x;
    const int C = (N + SCB - 1) / SCB;
    const int W = (C + 255) / 256;
    int s0 = b * C + t * W;
    int s1 = min(s0 + W, min((b + 1) * C, N));
    int s = 0;
    for (int i = s0; i < s1; ++i) s += deg[i];
    pre[t] = s;
    __syncthreads();
    // inclusive scan over pre -> convert to exclusive
    for (int d = 1; d < 256; d <<= 1) {
        int vv = (t >= d) ? pre[t - d] : 0;
        __syncthreads();
        if (t >= d) pre[t] += vv;
        __syncthreads();
    }
    int run = boff[b] + ((t == 0) ? 0 : pre[t - 1]);
    for (int i = s0; i < s1; ++i) {
        off[i] = run;
        cursor[i] = run;
        run += deg[i];
    }
}

__global__ void __launch_bounds__(256) scatter_kernel(const int* __restrict__ ei,
                                                      int* __restrict__ cursor,
                                                      int* __restrict__ ssrc, int E) {
    int e = blockIdx.x * 256 + threadIdx.x;
    if (e < E) {
        int pos = atomicAdd(&cursor[ei[E + e]], 1);
        ssrc[pos] = ei[e];
    }
}

// ======================= pull aggregation: wave per node, 16 lanes per edge, 4 edges in flight
__global__ void __launch_bounds__(256) agg_v4(
    const int* __restrict__ off, const int* __restrict__ ssrc,
    const float* __restrict__ A, const float* __restrict__ B,
    const float* __restrict__ We2, const float* __restrict__ be2,
    const float* __restrict__ h, float* __restrict__ aggr, int N)
{
    const int wid = threadIdx.x >> 6, lane = threadIdx.x & 63;
    const int node = blockIdx.x * 4 + wid;
    if (node >= N) return;
    const int g = lane >> 4;          // edge sub-group 0..3
    const int c8 = (lane & 15) * 8;   // 8 cols owned by this lane within its group

    const float4* Bp = (const float4*)(B + (size_t)node * D + c8);
    float4 b0 = Bp[0], b1 = Bp[1];
    const float4* Wp = (const float4*)(We2 + c8);
    float4 w0 = Wp[0], w1 = Wp[1];
    const float be = be2[0];

    float4 acc0 = make_float4(0.f,0.f,0.f,0.f);
    float4 acc1 = make_float4(0.f,0.f,0.f,0.f);

    const int s = off[node], e = off[node + 1];
    const int nit = (e - s + 3) >> 2;
    for (int it = 0; it < nit; ++it) {
        int j = s + it * 4 + g;
        bool valid = (j < e);
        int src = valid ? ssrc[j] : ssrc[s];
        const float4* Ap = (const float4*)(A + (size_t)src * D + c8);
        float4 a0 = Ap[0], a1 = Ap[1];
        const float4* Hp = (const float4*)(h + (size_t)src * D + c8);
        float4 h0 = Hp[0], h1 = Hp[1];
        float d = fmaxf(a0.x + b0.x, 0.f) * w0.x + fmaxf(a0.y + b0.y, 0.f) * w0.y
                + fmaxf(a0.z + b0.z, 0.f) * w0.z + fmaxf(a0.w + b0.w, 0.f) * w0.w
                + fmaxf(a1.x + b1.x, 0.f) * w1.x + fmaxf(a1.y + b1.y, 0.f) * w1.y
                + fmaxf(a1.z + b1.z, 0.f) * w1.z + fmaxf(a1.w + b1.w, 0.f) * w1.w;
        d += __shfl_xor(d, 1);
        d += __shfl_xor(d, 2);
        d += __shfl_xor(d, 4);
        d += __shfl_xor(d, 8);
        float wgt = valid ? 1.f / (1.f + expf(-(d + be))) : 0.f;
        acc0.x += wgt * h0.x; acc0.y += wgt * h0.y; acc0.z += wgt * h0.z; acc0.w += wgt * h0.w;
        acc1.x += wgt * h1.x; acc1.y += wgt * h1.y; acc1.z += wgt * h1.z; acc1.w += wgt * h1.w;
    }

    // combine the 4 sub-group partials (cols identical across groups)
    #pragma unroll
    for (int o = 16; o <= 32; o <<= 1) {
        acc0.x += __shfl_xor(acc0.x, o); acc0.y += __shfl_xor(acc0.y, o);
        acc0.z += __shfl_xor(acc0.z, o); acc0.w += __shfl_xor(acc0.w, o);
        acc1.x += __shfl_xor(acc1.x, o); acc1.y += __shfl_xor(acc1.y, o);
        acc1.z += __shfl_xor(acc1.z, o); acc1.w += __shfl_xor(acc1.w, o);
    }
    if (g == 0) {
        float4* Op = (float4*)(aggr + (size_t)node * D + c8);
        Op[0] = acc0;
        Op[1] = acc1;
    }
}

// ======================= gate + final LN (32 nodes/block)
__global__ void __launch_bounds__(256) gate_v4(
    const float* __restrict__ h, const float* __restrict__ aggr,
    const float* __restrict__ Wg, const float* __restrict__ bg,
    const float* __restrict__ g2, const float* __restrict__ bt2,
    float* __restrict__ out, int N)
{
    __shared__ float hs[NT][LP];
    __shared__ float as[NT][LP];
    const int t = threadIdx.x;
    const int q = t >> 6, lane = t & 63;
    const int c = lane;
    const int base = blockIdx.x * NT;

    {
        int node = t >> 3, c0 = (t & 7) * 16;
        size_t g = (size_t)min(base + node, N - 1) * D + c0;
        const float4* hsrc = (const float4*)(h + g);
        const float4* asrc = (const float4*)(aggr + g);
        float4* hd = (float4*)&hs[node][c0];
        float4* ad = (float4*)&as[node][c0];
        hd[0]=hsrc[0]; hd[1]=hsrc[1]; hd[2]=hsrc[2]; hd[3]=hsrc[3];
        ad[0]=asrc[0]; ad[1]=asrc[1]; ad[2]=asrc[2]; ad[3]=asrc[3];
    }
    __syncthreads();

    // gate pre-activation: h@Wg[0:128,:] + aggr@Wg[128:256,:]
    float acc[8][2];
    #pragma unroll
    for (int n = 0; n < 8; ++n) { acc[n][0] = 0.f; acc[n][1] = 0.f; }
    for (int k = 0; k < 128; k += 4) {
        float t00 = Wg[(k+0)*128 + c],    t01 = Wg[(k+0)*128 + c + 64];
        float t10 = Wg[(k+1)*128 + c],    t11 = Wg[(k+1)*128 + c + 64];
        float t20 = Wg[(k+2)*128 + c],    t21 = Wg[(k+2)*128 + c + 64];
        float t30 = Wg[(k+3)*128 + c],    t31 = Wg[(k+3)*128 + c + 64];
        float u00 = Wg[(k+128)*128 + c],  u01 = Wg[(k+128)*128 + c + 64];
        float u10 = Wg[(k+129)*128 + c],  u11 = Wg[(k+129)*128 + c + 64];
        float u20 = Wg[(k+130)*128 + c],  u21 = Wg[(k+130)*128 + c + 64];
        float u30 = Wg[(k+131)*128 + c],  u31 = Wg[(k+131)*128 + c + 64];
        #pragma unroll
        for (int n = 0; n < 8; ++n) {
            float4 hv = *(const float4*)&hs[q*8+n][k];
            float4 av = *(const float4*)&as[q*8+n][k];
            acc[n][0] += hv.x*t00 + hv.y*t10 + hv.z*t20 + hv.w*t30
                       + av.x*u00 + av.y*u10 + av.z*u20 + av.w*u30;
            acc[n][1] += hv.x*t01 + hv.y*t11 + hv.z*t21 + hv.w*t31
                       + av.x*u01 + av.y*u11 + av.z*u21 + av.w*u31;
        }
    }
    // gate combine -> overwrite hs with h_new
    {
        float bg0 = bg[c], bg1 = bg[c + 64];
        #pragma unroll
        for (int n = 0; n < 8; ++n) {
            int node = q*8 + n;
            float ga = 1.f / (1.f + expf(-(acc[n][0] + bg0)));
            float gb = 1.f / (1.f + expf(-(acc[n][1] + bg1)));
            float y0 = ga * as[node][c]      + (1.f - ga) * hs[node][c];
            float y1 = gb * as[node][c + 64] + (1.f - gb) * hs[node][c + 64];
            hs[node][c]      = y0;
            hs[node][c + 64] = y1;
        }
    }
    __syncthreads();

    {
        float gg0 = g2[2*lane], gg1 = g2[2*lane+1];
        float bb0 = bt2[2*lane], bb1 = bt2[2*lane+1];
        #pragma unroll
        for (int i = 0; i < 8; ++i) {
            int node = q * 8 + i;
            float v0 = hs[node][2*lane], v1 = hs[node][2*lane+1];
            float s = wave_allsum(v0 + v1);
            float qq = wave_allsum(v0*v0 + v1*v1);
            float m = s * (1.f/128.f);
            float var = qq * (1.f/128.f) - m*m;
            float rs = rsqrtf(var + 1e-5f);
            if (base + node < N) {
                float2 o = make_float2((v0 - m)*rs*gg0 + bb0, (v1 - m)*rs*gg1 + bb1);
                *(float2*)&out[(size_t)(base + node) * D + 2*lane] = o;
            }
        }
    }
}

extern "C" void kernel_launch(void* const* d_in, const int* in_sizes, int n_in,
                              void* d_out, int out_size, void* d_ws, size_t ws_size,
                              hipStream_t stream) {
    const float* x   = (const float*)d_in[0];
    const int*   ei  = (const int*)d_in[1];
    const float* W1  = (const float*)d_in[2];
    const float* b1  = (const float*)d_in[3];
    const float* g1  = (const float*)d_in[4];
    const float* bt1 = (const float*)d_in[5];
    const float* We1 = (const float*)d_in[6];
    const float* be1 = (const float*)d_in[7];
    const float* We2 = (const float*)d_in[8];
    const float* be2 = (const float*)d_in[9];
    const float* Wg  = (const float*)d_in[14];
    const float* bg  = (const float*)d_in[15];
    const float* g2  = (const float*)d_in[16];
    const float* bt2 = (const float*)d_in[17];

    const int N = in_sizes[0] / D;
    const int E = in_sizes[1] / 2;
    const size_t ND = (size_t)N * D;

    float* h    = (float*)d_ws;
    float* A    = h + ND;
    float* B    = A + ND;
    float* aggr = B + ND;
    int* deg    = (int*)(aggr + ND);
    int* off    = deg + (N + 1);
    int* cursor = off + (N + 1);
    int* ssrc   = cursor + (N + 1);
    int* bsum   = ssrc + E;
    int* boff   = bsum + SCB;

    (void)hipMemsetAsync(deg, 0, (size_t)(N + 1) * sizeof(int), stream);

    hist_kernel<<<(E + 255) / 256, 256, 0, stream>>>(ei, deg, E);
    scan_a<<<SCB, 256, 0, stream>>>(deg, bsum, N);
    scan_b<<<1, SCB, 0, stream>>>(bsum, boff, off, N);
    scan_c<<<SCB, 256, 0, stream>>>(deg, boff, off, cursor, N);
    scatter_kernel<<<(E + 255) / 256, 256, 0, stream>>>(ei, cursor, ssrc, E);

    const int nblk = (N + NT - 1) / NT;
    transform_v4<<<nblk, 256, 0, stream>>>(x, W1, b1, g1, bt1, We1, be1, h, A, B, N);
    agg_v4<<<(N + 3) / 4, 256, 0, stream>>>(off, ssrc, A, B, We2, be2, h, aggr, N);
    gate_v4<<<nblk, 256, 0, stream>>>(h, aggr, Wg, bg, g2, bt2, (float*)d_out, N);
}

// Round 11
// 392.428 us; speedup vs baseline: 3.5062x; 1.0272x over previous
//
#include <hip/hip_runtime.h>
#include <math.h>

#define D 128
#define NT 32
#define LP 132   // padded f32 LDS row
#define SCB 64   // scan blocks

__device__ __forceinline__ float wave_allsum(float v) {
    #pragma unroll
    for (int off = 32; off; off >>= 1) v += __shfl_xor(v, off);
    return v;
}

// ======================= transform: h=relu(LN(x@W1+b1)); A=h@We1_top+be1; B=h@We1_bot
// 32 nodes/block, 256 threads, barrier-free: wave q owns nodes q*8..q*8+7 end-to-end;
// lane owns cols c=lane and c+64, so each wave holds full rows in registers for LN.
__global__ void __launch_bounds__(256) transform_v5(
    const float* __restrict__ x, const float* __restrict__ W1, const float* __restrict__ b1,
    const float* __restrict__ g1, const float* __restrict__ bt1,
    const float* __restrict__ We1, const float* __restrict__ be1,
    float* __restrict__ h, float* __restrict__ A, float* __restrict__ B, int N)
{
    __shared__ float xs[NT][LP];
    __shared__ float hs[NT][LP];
    const int t = threadIdx.x;
    const int q = t >> 6, lane = t & 63;
    const int c = lane;
    const int base = blockIdx.x * NT;

    // stage x: thread t -> node t>>3 (wave q stages exactly its own nodes q*8..q*8+7)
    {
        int node = t >> 3, c0 = (t & 7) * 16;
        int gn = min(base + node, N - 1);
        const float4* src = (const float4*)(x + (size_t)gn * D + c0);
        float4* dst = (float4*)&xs[node][c0];
        dst[0] = src[0]; dst[1] = src[1]; dst[2] = src[2]; dst[3] = src[3];
    }
    // no __syncthreads: wave-local LDS rows only

    // GEMM1: y = x@W1  (native [k][n] weights, coalesced)
    float acc[8][2];
    #pragma unroll
    for (int n = 0; n < 8; ++n) { acc[n][0] = 0.f; acc[n][1] = 0.f; }
    for (int k = 0; k < 128; k += 4) {
        float w00 = W1[(k+0)*128 + c], w01 = W1[(k+0)*128 + c + 64];
        float w10 = W1[(k+1)*128 + c], w11 = W1[(k+1)*128 + c + 64];
        float w20 = W1[(k+2)*128 + c], w21 = W1[(k+2)*128 + c + 64];
        float w30 = W1[(k+3)*128 + c], w31 = W1[(k+3)*128 + c + 64];
        #pragma unroll
        for (int n = 0; n < 8; ++n) {
            float4 xv = *(const float4*)&xs[q*8+n][k];
            acc[n][0] += xv.x*w00 + xv.y*w10 + xv.z*w20 + xv.w*w30;
            acc[n][1] += xv.x*w01 + xv.y*w11 + xv.z*w21 + xv.w*w31;
        }
    }

    // LN + relu fully in registers (wave holds full rows); hs tile + global h
    {
        float b0 = b1[c], b1v = b1[c + 64];
        float gg0 = g1[c], gg1 = g1[c + 64];
        float bb0 = bt1[c], bb1 = bt1[c + 64];
        #pragma unroll
        for (int n = 0; n < 8; ++n) {
            int node = q * 8 + n;
            float v0 = acc[n][0] + b0, v1 = acc[n][1] + b1v;
            float s = wave_allsum(v0 + v1);
            float qq = wave_allsum(v0*v0 + v1*v1);
            float m = s * (1.f/128.f);
            float var = qq * (1.f/128.f) - m*m;
            float rs = rsqrtf(var + 1e-5f);
            float h0 = fmaxf((v0 - m)*rs*gg0 + bb0, 0.f);
            float h1 = fmaxf((v1 - m)*rs*gg1 + bb1, 0.f);
            hs[node][c]      = h0;
            hs[node][c + 64] = h1;
            int gn = base + node;
            if (gn < N) {
                h[(size_t)gn * D + c]      = h0;
                h[(size_t)gn * D + c + 64] = h1;
            }
        }
    }

    // GEMM2: A = h@We1[0:128,:] + be1 ; B = h@We1[128:256,:]  (wave-local hs rows)
    float aA[8][2], aB[8][2];
    #pragma unroll
    for (int n = 0; n < 8; ++n) { aA[n][0]=0.f; aA[n][1]=0.f; aB[n][0]=0.f; aB[n][1]=0.f; }
    for (int k = 0; k < 128; k += 4) {
        float t00 = We1[(k+0)*128 + c],   t01 = We1[(k+0)*128 + c + 64];
        float t10 = We1[(k+1)*128 + c],   t11 = We1[(k+1)*128 + c + 64];
        float t20 = We1[(k+2)*128 + c],   t21 = We1[(k+2)*128 + c + 64];
        float t30 = We1[(k+3)*128 + c],   t31 = We1[(k+3)*128 + c + 64];
        float u00 = We1[(k+128)*128 + c], u01 = We1[(k+128)*128 + c + 64];
        float u10 = We1[(k+129)*128 + c], u11 = We1[(k+129)*128 + c + 64];
        float u20 = We1[(k+130)*128 + c], u21 = We1[(k+130)*128 + c + 64];
        float u30 = We1[(k+131)*128 + c], u31 = We1[(k+131)*128 + c + 64];
        #pragma unroll
        for (int n = 0; n < 8; ++n) {
            float4 hv = *(const float4*)&hs[q*8+n][k];
            aA[n][0] += hv.x*t00 + hv.y*t10 + hv.z*t20 + hv.w*t30;
            aA[n][1] += hv.x*t01 + hv.y*t11 + hv.z*t21 + hv.w*t31;
            aB[n][0] += hv.x*u00 + hv.y*u10 + hv.z*u20 + hv.w*u30;
            aB[n][1] += hv.x*u01 + hv.y*u11 + hv.z*u21 + hv.w*u31;
        }
    }
    {
        float be0 = be1[c], be1v = be1[c + 64];
        #pragma unroll
        for (int n = 0; n < 8; ++n) {
            int gn = base + q*8 + n;
            if (gn < N) {
                A[(size_t)gn * D + c]      = aA[n][0] + be0;
                A[(size_t)gn * D + c + 64] = aA[n][1] + be1v;
                B[(size_t)gn * D + c]      = aB[n][0];
                B[(size_t)gn * D + c + 64] = aB[n][1];
            }
        }
    }
}

// ---- CSR build ----
__global__ void __launch_bounds__(256) hist_kernel(const int* __restrict__ ei,
                                                   int* __restrict__ deg, int E) {
    int e = blockIdx.x * 256 + threadIdx.x;
    if (e < E) atomicAdd(&deg[ei[E + e]], 1);
}

// phase a: block b sums its chunk of deg -> bsum[b]
__global__ void __launch_bounds__(256) scan_a(const int* __restrict__ deg,
                                              int* __restrict__ bsum, int N) {
    __shared__ int red[256];
    const int b = blockIdx.x, t = threadIdx.x;
    const int C = (N + SCB - 1) / SCB;
    const int W = (C + 255) / 256;
    int s0 = b * C + t * W;
    int s1 = min(s0 + W, min((b + 1) * C, N));
    int s = 0;
    for (int i = s0; i < s1; ++i) s += deg[i];
    red[t] = s;
    __syncthreads();
    #pragma unroll
    for (int d = 128; d; d >>= 1) {
        if (t < d) red[t] += red[t + d];
        __syncthreads();
    }
    if (t == 0) bsum[b] = red[0];
}

// phase c: block b computes its base offset from bsum locally, writes off/cursor
__global__ void __launch_bounds__(256) scan_c(const int* __restrict__ deg,
                                              const int* __restrict__ bsum,
                                              int* __restrict__ off,
                                              int* __restrict__ cursor, int N) {
    __shared__ int pre[256];
    __shared__ int bofs;
    const int b = blockIdx.x, t = threadIdx.x;
    const int C = (N + SCB - 1) / SCB;
    const int W = (C + 255) / 256;
    if (t == 0) {
        int r = 0;
        for (int i = 0; i < b; ++i) r += bsum[i];
        bofs = r;
        if (b == SCB - 1) off[N] = r + bsum[b];
    }
    int s0 = b * C + t * W;
    int s1 = min(s0 + W, min((b + 1) * C, N));
    int s = 0;
    for (int i = s0; i < s1; ++i) s += deg[i];
    pre[t] = s;
    __syncthreads();
    for (int d = 1; d < 256; d <<= 1) {
        int vv = (t >= d) ? pre[t - d] : 0;
        __syncthreads();
        if (t >= d) pre[t] += vv;
        __syncthreads();
    }
    int run = bofs + ((t == 0) ? 0 : pre[t - 1]);
    for (int i = s0; i < s1; ++i) {
        off[i] = run;
        cursor[i] = run;
        run += deg[i];
    }
}

__global__ void __launch_bounds__(256) scatter_kernel(const int* __restrict__ ei,
                                                      int* __restrict__ cursor,
                                                      int* __restrict__ ssrc, int E) {
    int e = blockIdx.x * 256 + threadIdx.x;
    if (e < E) {
        int pos = atomicAdd(&cursor[ei[E + e]], 1);
        ssrc[pos] = ei[e];
    }
}

// ======================= pull aggregation: wave/node, 16 lanes/edge, 8 edges in flight
__global__ void __launch_bounds__(256) agg_v5(
    const int* __restrict__ off, const int* __restrict__ ssrc,
    const float* __restrict__ A, const float* __restrict__ B,
    const float* __restrict__ We2, const float* __restrict__ be2,
    const float* __restrict__ h, float* __restrict__ aggr, int N)
{
    const int wid = threadIdx.x >> 6, lane = threadIdx.x & 63;
    const int node = blockIdx.x * 4 + wid;
    if (node >= N) return;
    const int g = lane >> 4;          // edge sub-group 0..3
    const int c8 = (lane & 15) * 8;   // 8 cols owned by this lane within its group

    const float4* Bp = (const float4*)(B + (size_t)node * D + c8);
    float4 b0 = Bp[0], b1 = Bp[1];
    const float4* Wp = (const float4*)(We2 + c8);
    float4 w0 = Wp[0], w1 = Wp[1];
    const float be = be2[0];

    float4 acc0 = make_float4(0.f,0.f,0.f,0.f);
    float4 acc1 = make_float4(0.f,0.f,0.f,0.f);

    const int s = off[node], e = off[node + 1];
    const int nit = (e - s + 7) >> 3;
    for (int it = 0; it < nit; ++it) {
        int ja = s + it * 8 + g * 2;
        int jb = ja + 1;
        int sa = ssrc[min(ja, e - 1)];
        int sb = ssrc[min(jb, e - 1)];
        const float4* Aa = (const float4*)(A + (size_t)sa * D + c8);
        const float4* Ab = (const float4*)(A + (size_t)sb * D + c8);
        const float4* Ha = (const float4*)(h + (size_t)sa * D + c8);
        const float4* Hb = (const float4*)(h + (size_t)sb * D + c8);
        float4 aa0 = Aa[0], aa1 = Aa[1], ab0 = Ab[0], ab1 = Ab[1];
        float4 ha0 = Ha[0], ha1 = Ha[1], hb0 = Hb[0], hb1 = Hb[1];
        float da = fmaxf(aa0.x + b0.x, 0.f) * w0.x + fmaxf(aa0.y + b0.y, 0.f) * w0.y
                 + fmaxf(aa0.z + b0.z, 0.f) * w0.z + fmaxf(aa0.w + b0.w, 0.f) * w0.w
                 + fmaxf(aa1.x + b1.x, 0.f) * w1.x + fmaxf(aa1.y + b1.y, 0.f) * w1.y
                 + fmaxf(aa1.z + b1.z, 0.f) * w1.z + fmaxf(aa1.w + b1.w, 0.f) * w1.w;
        float db = fmaxf(ab0.x + b0.x, 0.f) * w0.x + fmaxf(ab0.y + b0.y, 0.f) * w0.y
                 + fmaxf(ab0.z + b0.z, 0.f) * w0.z + fmaxf(ab0.w + b0.w, 0.f) * w0.w
                 + fmaxf(ab1.x + b1.x, 0.f) * w1.x + fmaxf(ab1.y + b1.y, 0.f) * w1.y
                 + fmaxf(ab1.z + b1.z, 0.f) * w1.z + fmaxf(ab1.w + b1.w, 0.f) * w1.w;
        da += __shfl_xor(da, 1);  db += __shfl_xor(db, 1);
        da += __shfl_xor(da, 2);  db += __shfl_xor(db, 2);
        da += __shfl_xor(da, 4);  db += __shfl_xor(db, 4);
        da += __shfl_xor(da, 8);  db += __shfl_xor(db, 8);
        float wa = (ja < e) ? 1.f / (1.f + expf(-(da + be))) : 0.f;
        float wb = (jb < e) ? 1.f / (1.f + expf(-(db + be))) : 0.f;
        acc0.x += wa * ha0.x + wb * hb0.x; acc0.y += wa * ha0.y + wb * hb0.y;
        acc0.z += wa * ha0.z + wb * hb0.z; acc0.w += wa * ha0.w + wb * hb0.w;
        acc1.x += wa * ha1.x + wb * hb1.x; acc1.y += wa * ha1.y + wb * hb1.y;
        acc1.z += wa * ha1.z + wb * hb1.z; acc1.w += wa * ha1.w + wb * hb1.w;
    }

    // combine the 4 sub-group partials (cols identical across groups)
    #pragma unroll
    for (int o = 16; o <= 32; o <<= 1) {
        acc0.x += __shfl_xor(acc0.x, o); acc0.y += __shfl_xor(acc0.y, o);
        acc0.z += __shfl_xor(acc0.z, o); acc0.w += __shfl_xor(acc0.w, o);
        acc1.x += __shfl_xor(acc1.x, o); acc1.y += __shfl_xor(acc1.y, o);
        acc1.z += __shfl_xor(acc1.z, o); acc1.w += __shfl_xor(acc1.w, o);
    }
    if (g == 0) {
        float4* Op = (float4*)(aggr + (size_t)node * D + c8);
        Op[0] = acc0;
        Op[1] = acc1;
    }
}

// ======================= gate + final LN (32 nodes/block, barrier-free)
__global__ void __launch_bounds__(256) gate_v5(
    const float* __restrict__ h, const float* __restrict__ aggr,
    const float* __restrict__ Wg, const float* __restrict__ bg,
    const float* __restrict__ g2, const float* __restrict__ bt2,
    float* __restrict__ out, int N)
{
    __shared__ float hs[NT][LP];
    __shared__ float as[NT][LP];
    const int t = threadIdx.x;
    const int q = t >> 6, lane = t & 63;
    const int c = lane;
    const int base = blockIdx.x * NT;

    {
        int node = t >> 3, c0 = (t & 7) * 16;
        size_t g = (size_t)min(base + node, N - 1) * D + c0;
        const float4* hsrc = (const float4*)(h + g);
        const float4* asrc = (const float4*)(aggr + g);
        float4* hd = (float4*)&hs[node][c0];
        float4* ad = (float4*)&as[node][c0];
        hd[0]=hsrc[0]; hd[1]=hsrc[1]; hd[2]=hsrc[2]; hd[3]=hsrc[3];
        ad[0]=asrc[0]; ad[1]=asrc[1]; ad[2]=asrc[2]; ad[3]=asrc[3];
    }
    // no __syncthreads: wave-local rows only

    float acc[8][2];
    #pragma unroll
    for (int n = 0; n < 8; ++n) { acc[n][0] = 0.f; acc[n][1] = 0.f; }
    for (int k = 0; k < 128; k += 4) {
        float t00 = Wg[(k+0)*128 + c],   t01 = Wg[(k+0)*128 + c + 64];
        float t10 = Wg[(k+1)*128 + c],   t11 = Wg[(k+1)*128 + c + 64];
        float t20 = Wg[(k+2)*128 + c],   t21 = Wg[(k+2)*128 + c + 64];
        float t30 = Wg[(k+3)*128 + c],   t31 = Wg[(k+3)*128 + c + 64];
        float u00 = Wg[(k+128)*128 + c], u01 = Wg[(k+128)*128 + c + 64];
        float u10 = Wg[(k+129)*128 + c], u11 = Wg[(k+129)*128 + c + 64];
        float u20 = Wg[(k+130)*128 + c], u21 = Wg[(k+130)*128 + c + 64];
        float u30 = Wg[(k+131)*128 + c], u31 = Wg[(k+131)*128 + c + 64];
        #pragma unroll
        for (int n = 0; n < 8; ++n) {
            float4 hv = *(const float4*)&hs[q*8+n][k];
            float4 av = *(const float4*)&as[q*8+n][k];
            acc[n][0] += hv.x*t00 + hv.y*t10 + hv.z*t20 + hv.w*t30
                       + av.x*u00 + av.y*u10 + av.z*u20 + av.w*u30;
            acc[n][1] += hv.x*t01 + hv.y*t11 + hv.z*t21 + hv.w*t31
                       + av.x*u01 + av.y*u11 + av.z*u21 + av.w*u31;
        }
    }

    // gate combine + final LN fully in registers
    {
        float bg0 = bg[c], bg1 = bg[c + 64];
        float gg0 = g2[c], gg1 = g2[c + 64];
        float bb0 = bt2[c], bb1 = bt2[c + 64];
        #pragma unroll
        for (int n = 0; n < 8; ++n) {
            int node = q*8 + n;
            float ga = 1.f / (1.f + expf(-(acc[n][0] + bg0)));
            float gb = 1.f / (1.f + expf(-(acc[n][1] + bg1)));
            float y0 = ga * as[node][c]      + (1.f - ga) * hs[node][c];
            float y1 = gb * as[node][c + 64] + (1.f - gb) * hs[node][c + 64];
            float s = wave_allsum(y0 + y1);
            float qq = wave_allsum(y0*y0 + y1*y1);
            float m = s * (1.f/128.f);
            float var = qq * (1.f/128.f) - m*m;
            float rs = rsqrtf(var + 1e-5f);
            int gn = base + node;
            if (gn < N) {
                out[(size_t)gn * D + c]      = (y0 - m)*rs*gg0 + bb0;
                out[(size_t)gn * D + c + 64] = (y1 - m)*rs*gg1 + bb1;
            }
        }
    }
}

extern "C" void kernel_launch(void* const* d_in, const int* in_sizes, int n_in,
                              void* d_out, int out_size, void* d_ws, size_t ws_size,
                              hipStream_t stream) {
    const float* x   = (const float*)d_in[0];
    const int*   ei  = (const int*)d_in[1];
    const float* W1  = (const float*)d_in[2];
    const float* b1  = (const float*)d_in[3];
    const float* g1  = (const float*)d_in[4];
    const float* bt1 = (const float*)d_in[5];
    const float* We1 = (const float*)d_in[6];
    const float* be1 = (const float*)d_in[7];
    const float* We2 = (const float*)d_in[8];
    const float* be2 = (const float*)d_in[9];
    const float* Wg  = (const float*)d_in[14];
    const float* bg  = (const float*)d_in[15];
    const float* g2  = (const float*)d_in[16];
    const float* bt2 = (const float*)d_in[17];

    const int N = in_sizes[0] / D;
    const int E = in_sizes[1] / 2;
    const size_t ND = (size_t)N * D;

    float* h    = (float*)d_ws;
    float* A    = h + ND;
    float* B    = A + ND;
    float* aggr = B + ND;
    int* deg    = (int*)(aggr + ND);
    int* off    = deg + (N + 1);
    int* cursor = off + (N + 1);
    int* ssrc   = cursor + (N + 1);
    int* bsum   = ssrc + E;

    (void)hipMemsetAsync(deg, 0, (size_t)(N + 1) * sizeof(int), stream);

    hist_kernel<<<(E + 255) / 256, 256, 0, stream>>>(ei, deg, E);
    scan_a<<<SCB, 256, 0, stream>>>(deg, bsum, N);
    scan_c<<<SCB, 256, 0, stream>>>(deg, bsum, off, cursor, N);
    scatter_kernel<<<(E + 255) / 256, 256, 0, stream>>>(ei, cursor, ssrc, E);

    const int nblk = (N + NT - 1) / NT;
    transform_v5<<<nblk, 256, 0, stream>>>(x, W1, b1, g1, bt1, We1, be1, h, A, B, N);
    agg_v5<<<(N + 3) / 4, 256, 0, stream>>>(off, ssrc, A, B, We2, be2, h, aggr, N);
    gate_v5<<<nblk, 256, 0, stream>>>(h, aggr, Wg, bg, g2, bt2, (float*)d_out, N);
}